// Round 1
// baseline (712.175 us; speedup 1.0000x reference)
//
#include <hip/hip_runtime.h>

#define NN 10000
#define NNP 10112  // 79*128 padded rows (slack reads harmless, never stored)
#define NE 320000
#define NG 64
#define D1 128
#define D2 256
#define MT 79      // row tiles of 128

typedef unsigned short u16;
typedef short v8s __attribute__((ext_vector_type(8)));
typedef float v4f __attribute__((ext_vector_type(4)));

__device__ __forceinline__ u16 f2bf(float x) {
    unsigned u = __float_as_uint(x);
    return (u16)((u + 0x7fffu + ((u >> 16) & 1u)) >> 16);
}
__device__ __forceinline__ float bf2f(u16 b) {
    return __uint_as_float(((unsigned)b) << 16);
}
__device__ __forceinline__ float sigm(float x) { return 1.f / (1.f + expf(-x)); }

// async global->LDS, 16B per lane; LDS dest = wave-uniform base + lane*16
#define GLDS16(gp, lp)                                                         \
    __builtin_amdgcn_global_load_lds(                                          \
        (__attribute__((address_space(1))) unsigned int*)(unsigned long long)(gp), \
        (__attribute__((address_space(3))) unsigned int*)(lp), 16, 0, 0)

// XCD-aware swizzle: 1-D grid of 80*NX blocks. xcd = bid&7 (round-robin HW
// assignment heuristic); each XCD covers row-tile band [xcd*10, xcd*10+10)
// for ALL col tiles -> its A slice + B stay L2-resident (kills the 4-8x
// A refetch seen in r4-r9 FETCH_SIZE).
#define SWIZZLE(bx, by)                          \
    const int bid_ = blockIdx.x;                 \
    const int l_ = bid_ >> 3;                    \
    const int by = (bid_ & 7) * 10 + l_ % 10;    \
    const int bx = l_ / 10;                      \
    if (by >= MT) return;

// =====================================================================
// GEMM1 (r4-proven): D = (Ah+Al)[M,K] @ (Bh+Bl)[4K,K]^T
// B rows [0,K) = w[it]^T -> m: Cm[R*K+gc] ; rows [K,4K) = whh (natural
// gate-major order) -> gh[R*3K + cc] = acc + bhh[cc]  (cc = gc-K).
// 128x128 tile, 4 waves 64x64, 16x16x32 mfma, BK=32, 3-term split-bf16,
// single-buffer LDS (dbuf regressed r5: grid-limited).
// =====================================================================
__global__ __launch_bounds__(256)
void mgh_k(const u16* __restrict__ Ah, const u16* __restrict__ Al,
           const u16* __restrict__ Bh, const u16* __restrict__ Bl,
           const float* __restrict__ bhh, float* __restrict__ Cm,
           float* __restrict__ gh, int K) {
    SWIZZLE(bx, by)
    __shared__ u16 lds[16384];
    const int tid = threadIdx.x;
    const int wave = tid >> 6, lane = tid & 63;
    const int wm = (wave >> 1) * 64, wn = (wave & 1) * 64;
    const int bm = by * 128, bn = bx * 128;
    const int quad = lane >> 4, r16 = lane & 15;

    v4f acc[4][4] = {};
    for (int k0 = 0; k0 < K; k0 += 32) {
#pragma unroll
        for (int j = 0; j < 2; ++j) {
            int row = j * 64 + lane;
            size_t aoff = (size_t)(bm + row) * K + k0 + wave * 8;
            size_t boff = (size_t)(bn + row) * K + k0 + wave * 8;
            int s = (wave * 128 + row) * 8;
            GLDS16(Ah + aoff, &lds[s]);
            GLDS16(Al + aoff, &lds[4096 + s]);
            GLDS16(Bh + boff, &lds[8192 + s]);
            GLDS16(Bl + boff, &lds[12288 + s]);
        }
        __syncthreads();
        v8s ah[4], al[4], bh[4], bl[4];
#pragma unroll
        for (int i = 0; i < 4; ++i) {
            int ra = (quad * 128 + wm + i * 16 + r16) * 8;
            int rb = (quad * 128 + wn + i * 16 + r16) * 8;
            ah[i] = *(const v8s*)&lds[ra];
            al[i] = *(const v8s*)&lds[4096 + ra];
            bh[i] = *(const v8s*)&lds[8192 + rb];
            bl[i] = *(const v8s*)&lds[12288 + rb];
        }
#pragma unroll
        for (int i = 0; i < 4; ++i)
#pragma unroll
            for (int j = 0; j < 4; ++j) {
                acc[i][j] = __builtin_amdgcn_mfma_f32_16x16x32_bf16(ah[i], bh[j], acc[i][j], 0, 0, 0);
                acc[i][j] = __builtin_amdgcn_mfma_f32_16x16x32_bf16(ah[i], bl[j], acc[i][j], 0, 0, 0);
                acc[i][j] = __builtin_amdgcn_mfma_f32_16x16x32_bf16(al[i], bh[j], acc[i][j], 0, 0, 0);
            }
        __syncthreads();
    }

    // epilogue: C/D layout col=lane&15, row=quad*4+reg
#pragma unroll
    for (int i = 0; i < 4; ++i) {
        int gr0 = bm + wm + i * 16 + quad * 4;
#pragma unroll
        for (int j = 0; j < 4; ++j) {
            int gc = bn + wn + j * 16 + r16;
            if (gc < K) {  // m part (block-uniform: K multiple of 128)
#pragma unroll
                for (int r = 0; r < 4; ++r) {
                    int gr = gr0 + r;
                    if (gr < NN) Cm[(size_t)gr * K + gc] = acc[i][j][r];
                }
            } else {       // gh part, natural layout [R][3K]
                int cc = gc - K;
                float bv = bhh[cc];
#pragma unroll
                for (int r = 0; r < 4; ++r) {
                    int gr = gr0 + r;
                    if (gr < NN) gh[(size_t)gr * 3 * K + cc] = acc[i][j][r] + bv;
                }
            }
        }
    }
}

// =====================================================================
// GEMM2 + GRU epilogue. B = wih gate-permuted (verified r7/r8):
// row jp = (c/16)*48 + g*16 + (c%16). Block 128 rows x 96 cols, wave
// 64x48; acc j = gate, all 3 gates of channel c in the SAME lane.
// Epilogue: gi = acc + bih, gh read from natural [R][3C] fp32 (+bhh
// already added), h from x bf16 hi/lo; full GRU; write new x hi/lo.
// In-place x safe: A operand is `a`; x touched only at owned (R,c).
// MODE 0: store stride OS. MODE 1: relu -> stride 256 (layer1->2).
// MODE 2: no store; atomicMax monotone-mapped into pool.
// =====================================================================
template<int MODE, int OS>
__global__ __launch_bounds__(256)
void giqru_k(const u16* __restrict__ Ah, const u16* __restrict__ Al,
             const u16* __restrict__ Bh, const u16* __restrict__ Bl,
             const float* __restrict__ gh, const float* __restrict__ bih,
             const u16* __restrict__ xh_in, const u16* __restrict__ xl_in,
             u16* __restrict__ xh_out, u16* __restrict__ xl_out,
             const int* __restrict__ batch, unsigned* __restrict__ pool,
             int C) {
    SWIZZLE(bx, by)
    __shared__ u16 lds[14336];  // A hi 0, A lo 4096, B hi 8192, B lo 11264
    const int tid = threadIdx.x;
    const int wave = tid >> 6, lane = tid & 63;
    const int wm = (wave >> 1) * 64;   // row half
    const int wn = (wave & 1) * 48;    // col half (16 channels x 3 gates)
    const int bm = by * 128;
    const int bcol = bx * 96;          // permuted B-row base
    const int quad = lane >> 4, r16 = lane & 15;

    v4f acc[4][3] = {};
    for (int k0 = 0; k0 < C; k0 += 32) {
#pragma unroll
        for (int j = 0; j < 2; ++j) {
            int row = j * 64 + lane;
            size_t g = (size_t)(bm + row) * C + k0 + wave * 8;
            int s = (wave * 128 + row) * 8;
            GLDS16(Ah + g, &lds[s]);
            GLDS16(Al + g, &lds[4096 + s]);
        }
        {
            int row = lane;
            size_t g = (size_t)(bcol + row) * C + k0 + wave * 8;
            int s = (wave * 96 + row) * 8;
            GLDS16(Bh + g, &lds[8192 + s]);
            GLDS16(Bl + g, &lds[11264 + s]);
            if (lane < 32) {
                row = 64 + lane;
                g = (size_t)(bcol + row) * C + k0 + wave * 8;
                s = (wave * 96 + row) * 8;
                GLDS16(Bh + g, &lds[8192 + s]);
                GLDS16(Bl + g, &lds[11264 + s]);
            }
        }
        __syncthreads();
        v8s fah[4], fal[4], fbh[3], fbl[3];
#pragma unroll
        for (int i = 0; i < 4; ++i) {
            int ra = (quad * 128 + wm + i * 16 + r16) * 8;
            fah[i] = *(const v8s*)&lds[ra];
            fal[i] = *(const v8s*)&lds[4096 + ra];
        }
#pragma unroll
        for (int g = 0; g < 3; ++g) {
            int rb = (quad * 96 + wn + g * 16 + r16) * 8;
            fbh[g] = *(const v8s*)&lds[8192 + rb];
            fbl[g] = *(const v8s*)&lds[11264 + rb];
        }
#pragma unroll
        for (int i = 0; i < 4; ++i)
#pragma unroll
            for (int g = 0; g < 3; ++g) {
                acc[i][g] = __builtin_amdgcn_mfma_f32_16x16x32_bf16(fah[i], fbh[g], acc[i][g], 0, 0, 0);
                acc[i][g] = __builtin_amdgcn_mfma_f32_16x16x32_bf16(fah[i], fbl[g], acc[i][g], 0, 0, 0);
                acc[i][g] = __builtin_amdgcn_mfma_f32_16x16x32_bf16(fal[i], fbh[g], acc[i][g], 0, 0, 0);
            }
        __syncthreads();
    }

    // epilogue: channel c per lane; gates in acc[.][0..2]
    const int c = (bx * 2 + (wn ? 1 : 0)) * 16 + r16;
    const float bir = bih[c], biz = bih[C + c], bin = bih[2 * C + c];
#pragma unroll
    for (int i = 0; i < 4; ++i) {
        int R0 = bm + wm + i * 16 + quad * 4;
#pragma unroll
        for (int r = 0; r < 4; ++r) {
            int R = R0 + r;
            if (R >= NN) continue;
            const float* gp = gh + (size_t)R * 3 * C + c;
            float ghr = gp[0];
            float ghz = gp[C];
            float ghn = gp[2 * C];
            float rr = sigm(acc[i][0][r] + bir + ghr);
            float zz = sigm(acc[i][1][r] + biz + ghz);
            float nn_ = tanhf(acc[i][2][r] + bin + rr * ghn);
            float h = bf2f(xh_in[(size_t)R * C + c]) + bf2f(xl_in[(size_t)R * C + c]);
            float o = (1.f - zz) * nn_ + zz * h;
            if (MODE == 2) {
                unsigned b = __float_as_uint(o);
                unsigned u = (b & 0x80000000u) ? ~b : (b | 0x80000000u);
                atomicMax(&pool[batch[R] * 256 + c], u);
            } else {
                if (MODE == 1) o = fmaxf(o, 0.f);
                u16 hh = f2bf(o);
                xh_out[(size_t)R * OS + c] = hh;
                xl_out[(size_t)R * OS + c] = f2bf(o - bf2f(hh));
            }
        }
    }
}

// =====================================================================
// CSR build
// =====================================================================
__global__ void count_k(const int* __restrict__ dst, int* __restrict__ cnt) {
    int e = blockIdx.x * blockDim.x + threadIdx.x;
    if (e < NE) atomicAdd(&cnt[dst[e]], 1);
}

__global__ void scan_k(const int* __restrict__ cnt, int* __restrict__ off,
                       int* __restrict__ cur) {
    __shared__ int ps[1024];
    const int tid = threadIdx.x;
    const int CH = (NN + 1023) / 1024;
    const int base = tid * CH;
    int s = 0;
    for (int i = 0; i < CH; ++i) {
        int idx = base + i;
        if (idx < NN) s += cnt[idx];
    }
    ps[tid] = s;
    __syncthreads();
    for (int d = 1; d < 1024; d <<= 1) {
        int v = (tid >= d) ? ps[tid - d] : 0;
        __syncthreads();
        ps[tid] += v;
        __syncthreads();
    }
    int run = (tid > 0) ? ps[tid - 1] : 0;
    for (int i = 0; i < CH; ++i) {
        int idx = base + i;
        if (idx <= NN) { off[idx] = run; if (idx < NN) cur[idx] = run; }
        if (idx < NN) run += cnt[idx];
    }
}

__global__ void fill_k(const int* __restrict__ src, const int* __restrict__ dst,
                       int* __restrict__ cur, int* __restrict__ elist) {
    int e = blockIdx.x * blockDim.x + threadIdx.x;
    if (e >= NE) return;
    int p = atomicAdd(&cur[dst[e]], 1);
    elist[p] = src[e];
}

// =====================================================================
// CSR gather, 4-deep pipeline: a[n,:] = sum m[src,:], bf16 hi/lo out
// =====================================================================
template<int C>
__global__ void gather_k(const float* __restrict__ m, const int* __restrict__ off,
                         const int* __restrict__ elist,
                         u16* __restrict__ ah, u16* __restrict__ al) {
    constexpr int LPN = C / 4;
    int t = blockIdx.x * blockDim.x + threadIdx.x;
    int node = t / LPN;
    if (node >= NN) return;
    int c = (t % LPN) * 4;
    int s0 = off[node], s1 = off[node + 1];
    v4f a0 = 0.f, a1 = 0.f, a2 = 0.f, a3 = 0.f;
    int i = s0;
    for (; i + 4 <= s1; i += 4) {
        int e0 = elist[i], e1 = elist[i + 1], e2 = elist[i + 2], e3 = elist[i + 3];
        v4f v0 = *(const v4f*)(m + (size_t)e0 * C + c);
        v4f v1 = *(const v4f*)(m + (size_t)e1 * C + c);
        v4f v2 = *(const v4f*)(m + (size_t)e2 * C + c);
        v4f v3 = *(const v4f*)(m + (size_t)e3 * C + c);
        a0 += v0; a1 += v1; a2 += v2; a3 += v3;
    }
    for (; i < s1; ++i) {
        int e = elist[i];
        a0 += *(const v4f*)(m + (size_t)e * C + c);
    }
    v4f acc = (a0 + a1) + (a2 + a3);
    ushort4 h, l;
    h.x = f2bf(acc[0]); l.x = f2bf(acc[0] - bf2f(h.x));
    h.y = f2bf(acc[1]); l.y = f2bf(acc[1] - bf2f(h.y));
    h.z = f2bf(acc[2]); l.z = f2bf(acc[2] - bf2f(h.z));
    h.w = f2bf(acc[3]); l.w = f2bf(acc[3] - bf2f(h.w));
    *(ushort4*)(ah + (size_t)node * C + c) = h;
    *(ushort4*)(al + (size_t)node * C + c) = l;
}

// =====================================================================
// prep_k: weight transforms + x init, one launch.
// B1cat[it] [512,128]:  rows 0..127 = w1[it]^T, rows 128..511 = whh1 as-is
// B2cat[it] [1024,256]: rows 0..255 = w2[it]^T, rows 256..1023 = whh2 as-is
// Wi1/Wi2: wih gate-permuted (jp = (c/16)*48 + g*16 + (c%16)).
// =====================================================================
__global__ void prep_k(const float* __restrict__ w1, const float* __restrict__ w2,
                       const float* __restrict__ wih1, const float* __restrict__ whh1,
                       const float* __restrict__ wih2, const float* __restrict__ whh2,
                       const float* __restrict__ xin,
                       u16* __restrict__ B1h, u16* __restrict__ B1l,
                       u16* __restrict__ B2h, u16* __restrict__ B2l,
                       u16* __restrict__ Wi1h, u16* __restrict__ Wi1l,
                       u16* __restrict__ Wi2h, u16* __restrict__ Wi2l,
                       u16* __restrict__ xh, u16* __restrict__ xl) {
    const int n1 = 3 * D1 * D1;  // 49152
    const int n2 = 3 * D2 * D2;  // 196608
    int t = blockIdx.x * blockDim.x + threadIdx.x;
    if (t < n1) {  // w1 transpose -> B1 rows 0..127
        int l = t / (D1 * D1), rem = t - l * (D1 * D1);
        int k = rem / D1, n = rem - k * D1;
        float v = w1[t]; u16 h = f2bf(v);
        int o = (l * 512 + n) * D1 + k;
        B1h[o] = h; B1l[o] = f2bf(v - bf2f(h)); return;
    }
    t -= n1;
    if (t < n1) {  // whh1 as-is, replicate x3 -> B1 rows 128..511
        float v = whh1[t]; u16 h = f2bf(v), lo = f2bf(v - bf2f(h));
        int r = t / D1, k = t - r * D1;
#pragma unroll
        for (int l = 0; l < 3; ++l) {
            int o = (l * 512 + 128 + r) * D1 + k;
            B1h[o] = h; B1l[o] = lo;
        }
        return;
    }
    t -= n1;
    if (t < n2) {  // w2 transpose -> B2 rows 0..255
        int l = t / (D2 * D2), rem = t - l * (D2 * D2);
        int k = rem / D2, n = rem - k * D2;
        float v = w2[t]; u16 h = f2bf(v);
        int o = (l * 1024 + n) * D2 + k;
        B2h[o] = h; B2l[o] = f2bf(v - bf2f(h)); return;
    }
    t -= n2;
    if (t < n2) {  // whh2 as-is, replicate x3 -> B2 rows 256..1023
        float v = whh2[t]; u16 h = f2bf(v), lo = f2bf(v - bf2f(h));
        int r = t / D2, k = t - r * D2;
#pragma unroll
        for (int l = 0; l < 3; ++l) {
            int o = (l * 1024 + 256 + r) * D2 + k;
            B2h[o] = h; B2l[o] = lo;
        }
        return;
    }
    t -= n2;
    if (t < n1) {  // wih1 gate-permute
        int j = t / D1, k = t - j * D1;
        int g = j >> 7, c = j & 127;
        int jp = (c >> 4) * 48 + g * 16 + (c & 15);
        float v = wih1[t]; u16 h = f2bf(v);
        Wi1h[jp * D1 + k] = h; Wi1l[jp * D1 + k] = f2bf(v - bf2f(h)); return;
    }
    t -= n1;
    if (t < n2) {  // wih2 gate-permute
        int j = t / D2, k = t - j * D2;
        int g = j >> 8, c = j & 255;
        int jp = (c >> 4) * 48 + g * 16 + (c & 15);
        float v = wih2[t]; u16 h = f2bf(v);
        Wi2h[jp * D2 + k] = h; Wi2l[jp * D2 + k] = f2bf(v - bf2f(h)); return;
    }
    t -= n2;
    if (t < NN * D1) {  // x init (bf16 hi/lo, stride 128)
        float v = xin[t];
        u16 h = f2bf(v);
        xh[t] = h;
        xl[t] = f2bf(v - bf2f(h));
    }
}

// zero cols 128..255 of the layer-2 x buffer (stride 256)
__global__ void pad_k(u16* __restrict__ xh, u16* __restrict__ xl) {
    int t = blockIdx.x * blockDim.x + threadIdx.x;
    if (t >= NN * 128) return;
    int n = t >> 7, c = 128 + (t & 127);
    xh[n * 256 + c] = 0;
    xl[n * 256 + c] = 0;
}

__global__ void pool_init_k(unsigned* __restrict__ pool) {
    int t = blockIdx.x * blockDim.x + threadIdx.x;
    if (t < NG * D2) pool[t] = 0x007FFFFFu;  // mapped(-inf)
}

__global__ void fc_k(const unsigned* __restrict__ pool, const float* __restrict__ w,
                     const float* __restrict__ b, float* __restrict__ out) {
    int t = blockIdx.x * blockDim.x + threadIdx.x;
    if (t >= NG * 6) return;
    int g = t / 6, o = t - g * 6;
    float s = b[o];
    for (int c = 0; c < D2; ++c) {
        unsigned u = pool[g * D2 + c];
        unsigned bits = (u & 0x80000000u) ? (u ^ 0x80000000u) : ~u;
        s += __uint_as_float(bits) * w[o * D2 + c];
    }
    out[t] = s;
}

// =======================================================================
extern "C" void kernel_launch(void* const* d_in, const int* in_sizes, int n_in,
                              void* d_out, int out_size, void* d_ws, size_t ws_size,
                              hipStream_t stream) {
    const float* x_in = (const float*)d_in[0];
    const int* ei = (const int*)d_in[1];
    const int* src = ei;
    const int* dst = ei + NE;
    const int* batch = (const int*)d_in[2];
    const float* w1   = (const float*)d_in[3];
    const float* wih1 = (const float*)d_in[4];
    const float* whh1 = (const float*)d_in[5];
    const float* bih1 = (const float*)d_in[6];
    const float* bhh1 = (const float*)d_in[7];
    const float* w2   = (const float*)d_in[8];
    const float* wih2 = (const float*)d_in[9];
    const float* whh2 = (const float*)d_in[10];
    const float* bih2 = (const float*)d_in[11];
    const float* bhh2 = (const float*)d_in[12];
    const float* fcw  = (const float*)d_in[13];
    const float* fcb  = (const float*)d_in[14];
    float* out = (float*)d_out;

    // ---- workspace (~75 MB) ----
    float* ws = (float*)d_ws;
    float* mbuf = ws;                          // [NNP,256] fp32 (L1: stride 128)
    float* gh   = mbuf + NNP * 256;            // [NNP,768] fp32 natural layout
    u16* a_h  = (u16*)(gh + (size_t)NNP * 768);// [NNP,256]
    u16* a_l  = a_h + NNP * 256;
    u16* xA_h = a_l + NNP * 256;               // [NNP,128]
    u16* xA_l = xA_h + NNP * 128;
    u16* xB_h = xA_l + NNP * 128;              // [NNP,256]
    u16* xB_l = xB_h + NNP * 256;
    u16* B1h  = xB_l + NNP * 256;              // [3][512][128]
    u16* B1l  = B1h + 3 * 512 * D1;
    u16* B2h  = B1l + 3 * 512 * D1;            // [3][1024][256]
    u16* B2l  = B2h + 3 * 1024 * D2;
    u16* Wi1h = B2l + 3 * 1024 * D2;           // [384,128] permuted
    u16* Wi1l = Wi1h + 3 * D1 * D1;
    u16* Wi2h = Wi1l + 3 * D1 * D1;            // [768,256] permuted
    u16* Wi2l = Wi2h + 3 * D2 * D2;
    int* cnt   = (int*)(Wi2l + 3 * D2 * D2);
    int* off   = cnt + NN;
    int* cur   = off + NN + 1;
    int* elist = cur + NN;
    unsigned* pool = (unsigned*)(elist + NE);

    // ---- CSR + prep + pad + pool init ----
    hipMemsetAsync(cnt, 0, NN * sizeof(int), stream);
    count_k<<<(NE + 255) / 256, 256, 0, stream>>>(dst, cnt);
    scan_k<<<1, 1024, 0, stream>>>(cnt, off, cur);
    fill_k<<<(NE + 255) / 256, 256, 0, stream>>>(src, dst, cur, elist);
    {
        int total = 2 * (3 * D1 * D1) + 2 * (3 * D2 * D2) +
                    (3 * D1 * D1) + (3 * D2 * D2) + NN * D1;
        prep_k<<<(total + 255) / 256, 256, 0, stream>>>(
            w1, w2, wih1, whh1, wih2, whh2, x_in,
            B1h, B1l, B2h, B2l, Wi1h, Wi1l, Wi2h, Wi2l, xA_h, xA_l);
    }
    pad_k<<<(NN * 128 + 255) / 256, 256, 0, stream>>>(xB_h, xB_l);
    pool_init_k<<<(NG * D2 + 255) / 256, 256, 0, stream>>>(pool);

    // swizzled 1-D grids: 80 * NX blocks, NX = C/32 col tiles
    const int G1 = 80 * (D1 / 32);  // 320
    const int G2 = 80 * (D2 / 32);  // 640

    // ---------------- layer 1 (C = 128) ----------------
    for (int it = 0; it < 3; ++it) {
        const int C = D1;
        mgh_k<<<G1, 256, 0, stream>>>(
            xA_h, xA_l, B1h + it * 512 * C, B1l + it * 512 * C,
            bhh1, mbuf, gh, C);
        gather_k<D1><<<(NN * (D1 / 4) + 255) / 256, 256, 0, stream>>>(
            mbuf, off, elist, a_h, a_l);
        if (it < 2)
            giqru_k<0, 128><<<G1, 256, 0, stream>>>(
                a_h, a_l, Wi1h, Wi1l, gh, bih1,
                xA_h, xA_l, xA_h, xA_l, nullptr, nullptr, C);
        else  // relu + write into xB (stride 256; pad cols pre-zeroed)
            giqru_k<1, 256><<<G1, 256, 0, stream>>>(
                a_h, a_l, Wi1h, Wi1l, gh, bih1,
                xA_h, xA_l, xB_h, xB_l, nullptr, nullptr, C);
    }

    // ---------------- layer 2 (C = 256) ----------------
    for (int it = 0; it < 3; ++it) {
        const int C = D2;
        mgh_k<<<G2, 256, 0, stream>>>(
            xB_h, xB_l, B2h + it * 1024 * C, B2l + it * 1024 * C,
            bhh2, mbuf, gh, C);
        gather_k<D2><<<(NN * (D2 / 4) + 255) / 256, 256, 0, stream>>>(
            mbuf, off, elist, a_h, a_l);
        if (it < 2)
            giqru_k<0, 256><<<G2, 256, 0, stream>>>(
                a_h, a_l, Wi2h, Wi2l, gh, bih2,
                xB_h, xB_l, xB_h, xB_l, nullptr, nullptr, C);
        else  // final: fused segment-max pool
            giqru_k<2, 256><<<G2, 256, 0, stream>>>(
                a_h, a_l, Wi2h, Wi2l, gh, bih2,
                xB_h, xB_l, nullptr, nullptr, batch, pool, C);
    }

    fc_k<<<1, 512, 0, stream>>>(pool, fcw, fcb, out);
}

// Round 2
// 692.996 us; speedup vs baseline: 1.0277x; 1.0277x over previous
//
#include <hip/hip_runtime.h>

#define NN 10000
#define NNP 10112  // 79*128 padded rows (slack reads harmless, never stored)
#define NE 320000
#define NG 64
#define D1 128
#define D2 256
#define MT 79      // row tiles of 128

typedef unsigned short u16;
typedef short v8s __attribute__((ext_vector_type(8)));
typedef float v4f __attribute__((ext_vector_type(4)));

__device__ __forceinline__ u16 f2bf(float x) {
    unsigned u = __float_as_uint(x);
    return (u16)((u + 0x7fffu + ((u >> 16) & 1u)) >> 16);
}
__device__ __forceinline__ float bf2f(u16 b) {
    return __uint_as_float(((unsigned)b) << 16);
}
__device__ __forceinline__ float sigm(float x) { return 1.f / (1.f + __expf(-x)); }
__device__ __forceinline__ float tanh_f(float x) {
    float cx = fminf(fmaxf(x, -15.f), 15.f);   // clamp so __expf can't overflow
    float e = __expf(2.f * cx);
    return (e - 1.f) / (e + 1.f);
}

#define MF(d, a, b) d = __builtin_amdgcn_mfma_f32_16x16x32_bf16(a, b, d, 0, 0, 0)

// async global->LDS, 16B per lane; LDS dest = wave-uniform base + lane*16
#define GLDS16(gp, lp)                                                         \
    __builtin_amdgcn_global_load_lds(                                          \
        (__attribute__((address_space(1))) unsigned int*)(unsigned long long)(gp), \
        (__attribute__((address_space(3))) unsigned int*)(lp), 16, 0, 0)

// XCD-aware swizzle: 1-D grid of 80*NX blocks. xcd = bid&7; each XCD covers
// row-tile band [xcd*10, xcd*10+10) for ALL col tiles -> A slice + B stay
// L2-resident.
#define SWIZZLE(bx, by)                          \
    const int bid_ = blockIdx.x;                 \
    const int l_ = bid_ >> 3;                    \
    const int by = (bid_ & 7) * 10 + l_ % 10;    \
    const int bx = l_ / 10;                      \
    if (by >= MT) return;

// =====================================================================
// mm_k: m = x @ w[it]  (B = w^T, hi/lo split). 128x128 tile, 4 waves
// 64x64, 16x16x32 mfma, BK=32, 3-term split-bf16. Grid (MT, K/128).
// (gh is gone: it is now fused into giqru_k's accumulators.)
// =====================================================================
__global__ __launch_bounds__(256)
void mm_k(const u16* __restrict__ Ah, const u16* __restrict__ Al,
          const u16* __restrict__ Bh, const u16* __restrict__ Bl,
          float* __restrict__ Cm, int K) {
    const int by = blockIdx.x, bx = blockIdx.y;
    __shared__ u16 lds[16384];
    const int tid = threadIdx.x;
    const int wave = tid >> 6, lane = tid & 63;
    const int wm = (wave >> 1) * 64, wn = (wave & 1) * 64;
    const int bm = by * 128, bn = bx * 128;
    const int quad = lane >> 4, r16 = lane & 15;

    v4f acc[4][4] = {};
    for (int k0 = 0; k0 < K; k0 += 32) {
#pragma unroll
        for (int j = 0; j < 2; ++j) {
            int row = j * 64 + lane;
            size_t aoff = (size_t)(bm + row) * K + k0 + wave * 8;
            size_t boff = (size_t)(bn + row) * K + k0 + wave * 8;
            int s = (wave * 128 + row) * 8;
            GLDS16(Ah + aoff, &lds[s]);
            GLDS16(Al + aoff, &lds[4096 + s]);
            GLDS16(Bh + boff, &lds[8192 + s]);
            GLDS16(Bl + boff, &lds[12288 + s]);
        }
        __syncthreads();
        v8s ah[4], al[4], bh[4], bl[4];
#pragma unroll
        for (int i = 0; i < 4; ++i) {
            int ra = (quad * 128 + wm + i * 16 + r16) * 8;
            int rb = (quad * 128 + wn + i * 16 + r16) * 8;
            ah[i] = *(const v8s*)&lds[ra];
            al[i] = *(const v8s*)&lds[4096 + ra];
            bh[i] = *(const v8s*)&lds[8192 + rb];
            bl[i] = *(const v8s*)&lds[12288 + rb];
        }
#pragma unroll
        for (int i = 0; i < 4; ++i)
#pragma unroll
            for (int j = 0; j < 4; ++j) {
                MF(acc[i][j], ah[i], bh[j]);
                MF(acc[i][j], ah[i], bl[j]);
                MF(acc[i][j], al[i], bh[j]);
            }
        __syncthreads();
    }
    // C/D layout: col=lane&15, row=quad*4+reg
#pragma unroll
    for (int i = 0; i < 4; ++i) {
        int gr0 = bm + wm + i * 16 + quad * 4;
#pragma unroll
        for (int j = 0; j < 4; ++j) {
            int gc = bn + wn + j * 16 + r16;
#pragma unroll
            for (int r = 0; r < 4; ++r) {
                int gr = gr0 + r;
                if (gr < NN) Cm[(size_t)gr * K + gc] = acc[i][j][r];
            }
        }
    }
}

// =====================================================================
// giqru_k: FUSED  gi = a@wih^T, gh = x@whh^T, GRU update — no gh
// round-trip through HBM. acc[i][0]=ir+hr (fused sum), [1]=iz+hz,
// [2]=in, [3]=hn (kept separate for the r* gating).
// Block 128 rows x 32 channels (x3 gates), 4 waves 64row x 16chan.
// Wi/Wh both gate-permuted: row jp = (c/16)*48 + g*16 + (c%16).
// x is a full GEMM operand now -> ping-pong buffers (no in-place).
// MODE 0: store stride OS. MODE 1: relu -> stride 256 (layer1->2).
// MODE 2: no store; atomicMax monotone-mapped into pool.
// =====================================================================
template<int MODE, int OS>
__global__ __launch_bounds__(256)
void giqru_k(const u16* __restrict__ Ah, const u16* __restrict__ Al,
             const u16* __restrict__ Xh, const u16* __restrict__ Xl,
             const u16* __restrict__ WiH, const u16* __restrict__ WiL,
             const u16* __restrict__ WhH, const u16* __restrict__ WhL,
             const float* __restrict__ bih, const float* __restrict__ bhh,
             u16* __restrict__ xh_out, u16* __restrict__ xl_out,
             const int* __restrict__ batch, unsigned* __restrict__ pool,
             int C) {
    SWIZZLE(bx, by)
    // a hi 0, a lo 4096, x hi 8192, x lo 12288,
    // Wi hi 16384, Wi lo 19456, Wh hi 22528, Wh lo 25600  (u16 idx)
    __shared__ u16 lds[28672];  // 56 KB
    const int tid = threadIdx.x;
    const int wave = tid >> 6, lane = tid & 63;
    const int wm = (wave >> 1) * 64;   // row half
    const int wn = (wave & 1) * 48;    // col half (16 channels x 3 gates)
    const int bm = by * 128;
    const int bcol = bx * 96;          // permuted weight-row base
    const int quad = lane >> 4, r16 = lane & 15;

    v4f acc[4][4] = {};
    for (int k0 = 0; k0 < C; k0 += 32) {
#pragma unroll
        for (int j = 0; j < 2; ++j) {
            int row = j * 64 + lane;
            size_t g = (size_t)(bm + row) * C + k0 + wave * 8;
            int s = (wave * 128 + row) * 8;
            GLDS16(Ah + g, &lds[s]);
            GLDS16(Al + g, &lds[4096 + s]);
            GLDS16(Xh + g, &lds[8192 + s]);
            GLDS16(Xl + g, &lds[12288 + s]);
        }
        {
            int row = lane;
            size_t g = (size_t)(bcol + row) * C + k0 + wave * 8;
            int s = (wave * 96 + row) * 8;
            GLDS16(WiH + g, &lds[16384 + s]);
            GLDS16(WiL + g, &lds[19456 + s]);
            GLDS16(WhH + g, &lds[22528 + s]);
            GLDS16(WhL + g, &lds[25600 + s]);
            if (lane < 32) {
                row = 64 + lane;
                g = (size_t)(bcol + row) * C + k0 + wave * 8;
                s = (wave * 96 + row) * 8;
                GLDS16(WiH + g, &lds[16384 + s]);
                GLDS16(WiL + g, &lds[19456 + s]);
                GLDS16(WhH + g, &lds[22528 + s]);
                GLDS16(WhL + g, &lds[25600 + s]);
            }
        }
        __syncthreads();
        v8s wiH[3], wiL[3], whH[3], whL[3];
#pragma unroll
        for (int g = 0; g < 3; ++g) {
            int rb = (quad * 96 + wn + g * 16 + r16) * 8;
            wiH[g] = *(const v8s*)&lds[16384 + rb];
            wiL[g] = *(const v8s*)&lds[19456 + rb];
            whH[g] = *(const v8s*)&lds[22528 + rb];
            whL[g] = *(const v8s*)&lds[25600 + rb];
        }
#pragma unroll
        for (int i = 0; i < 4; ++i) {
            int ra = (quad * 128 + wm + i * 16 + r16) * 8;
            v8s fah = *(const v8s*)&lds[ra];
            v8s fal = *(const v8s*)&lds[4096 + ra];
            v8s fxh = *(const v8s*)&lds[8192 + ra];
            v8s fxl = *(const v8s*)&lds[12288 + ra];
            // r gate: a.wih_r + x.whh_r fused into one accumulator
            MF(acc[i][0], fah, wiH[0]); MF(acc[i][0], fah, wiL[0]); MF(acc[i][0], fal, wiH[0]);
            MF(acc[i][0], fxh, whH[0]); MF(acc[i][0], fxh, whL[0]); MF(acc[i][0], fxl, whH[0]);
            // z gate
            MF(acc[i][1], fah, wiH[1]); MF(acc[i][1], fah, wiL[1]); MF(acc[i][1], fal, wiH[1]);
            MF(acc[i][1], fxh, whH[1]); MF(acc[i][1], fxh, whL[1]); MF(acc[i][1], fxl, whH[1]);
            // in (input n-gate, separate)
            MF(acc[i][2], fah, wiH[2]); MF(acc[i][2], fah, wiL[2]); MF(acc[i][2], fal, wiH[2]);
            // hn (hidden n-gate, separate: gated by r)
            MF(acc[i][3], fxh, whH[2]); MF(acc[i][3], fxh, whL[2]); MF(acc[i][3], fxl, whH[2]);
        }
        __syncthreads();
    }

    // epilogue: pure-register GRU; h re-read from L2-warm x
    const int c = bx * 32 + (wn ? 16 : 0) + r16;
    const float br = bih[c] + bhh[c];
    const float bz = bih[C + c] + bhh[C + c];
    const float bi_n = bih[2 * C + c];
    const float bh_n = bhh[2 * C + c];
#pragma unroll
    for (int i = 0; i < 4; ++i) {
        int R0 = bm + wm + i * 16 + quad * 4;
#pragma unroll
        for (int r = 0; r < 4; ++r) {
            int R = R0 + r;
            if (R >= NN) continue;
            float rr = sigm(acc[i][0][r] + br);
            float zz = sigm(acc[i][1][r] + bz);
            float nn_ = tanh_f(acc[i][2][r] + bi_n + rr * (acc[i][3][r] + bh_n));
            float h = bf2f(Xh[(size_t)R * C + c]) + bf2f(Xl[(size_t)R * C + c]);
            float o = (1.f - zz) * nn_ + zz * h;
            if (MODE == 2) {
                unsigned b = __float_as_uint(o);
                unsigned u = (b & 0x80000000u) ? ~b : (b | 0x80000000u);
                atomicMax(&pool[batch[R] * 256 + c], u);
            } else {
                if (MODE == 1) o = fmaxf(o, 0.f);
                u16 hh = f2bf(o);
                xh_out[(size_t)R * OS + c] = hh;
                xl_out[(size_t)R * OS + c] = f2bf(o - bf2f(hh));
            }
        }
    }
}

// =====================================================================
// CSR build
// =====================================================================
__global__ void count_k(const int* __restrict__ dst, int* __restrict__ cnt) {
    int e = blockIdx.x * blockDim.x + threadIdx.x;
    if (e < NE) atomicAdd(&cnt[dst[e]], 1);
}

__global__ void scan_k(const int* __restrict__ cnt, int* __restrict__ off,
                       int* __restrict__ cur) {
    __shared__ int ps[1024];
    const int tid = threadIdx.x;
    const int CH = (NN + 1023) / 1024;
    const int base = tid * CH;
    int s = 0;
    for (int i = 0; i < CH; ++i) {
        int idx = base + i;
        if (idx < NN) s += cnt[idx];
    }
    ps[tid] = s;
    __syncthreads();
    for (int d = 1; d < 1024; d <<= 1) {
        int v = (tid >= d) ? ps[tid - d] : 0;
        __syncthreads();
        ps[tid] += v;
        __syncthreads();
    }
    int run = (tid > 0) ? ps[tid - 1] : 0;
    for (int i = 0; i < CH; ++i) {
        int idx = base + i;
        if (idx <= NN) { off[idx] = run; if (idx < NN) cur[idx] = run; }
        if (idx < NN) run += cnt[idx];
    }
}

__global__ void fill_k(const int* __restrict__ src, const int* __restrict__ dst,
                       int* __restrict__ cur, int* __restrict__ elist) {
    int e = blockIdx.x * blockDim.x + threadIdx.x;
    if (e >= NE) return;
    int p = atomicAdd(&cur[dst[e]], 1);
    elist[p] = src[e];
}

// =====================================================================
// CSR gather, 4-deep pipeline: a[n,:] = sum m[src,:], bf16 hi/lo out
// =====================================================================
template<int C>
__global__ void gather_k(const float* __restrict__ m, const int* __restrict__ off,
                         const int* __restrict__ elist,
                         u16* __restrict__ ah, u16* __restrict__ al) {
    constexpr int LPN = C / 4;
    int t = blockIdx.x * blockDim.x + threadIdx.x;
    int node = t / LPN;
    if (node >= NN) return;
    int c = (t % LPN) * 4;
    int s0 = off[node], s1 = off[node + 1];
    v4f a0 = 0.f, a1 = 0.f, a2 = 0.f, a3 = 0.f;
    int i = s0;
    for (; i + 4 <= s1; i += 4) {
        int e0 = elist[i], e1 = elist[i + 1], e2 = elist[i + 2], e3 = elist[i + 3];
        v4f v0 = *(const v4f*)(m + (size_t)e0 * C + c);
        v4f v1 = *(const v4f*)(m + (size_t)e1 * C + c);
        v4f v2 = *(const v4f*)(m + (size_t)e2 * C + c);
        v4f v3 = *(const v4f*)(m + (size_t)e3 * C + c);
        a0 += v0; a1 += v1; a2 += v2; a3 += v3;
    }
    for (; i < s1; ++i) {
        int e = elist[i];
        a0 += *(const v4f*)(m + (size_t)e * C + c);
    }
    v4f acc = (a0 + a1) + (a2 + a3);
    ushort4 h, l;
    h.x = f2bf(acc[0]); l.x = f2bf(acc[0] - bf2f(h.x));
    h.y = f2bf(acc[1]); l.y = f2bf(acc[1] - bf2f(h.y));
    h.z = f2bf(acc[2]); l.z = f2bf(acc[2] - bf2f(h.z));
    h.w = f2bf(acc[3]); l.w = f2bf(acc[3] - bf2f(h.w));
    *(ushort4*)(ah + (size_t)node * C + c) = h;
    *(ushort4*)(al + (size_t)node * C + c) = l;
}

// =====================================================================
// prep_k: weight transforms + x init, one launch.
// B1[it] [128,128] = w1[it]^T ; B2[it] [256,256] = w2[it]^T
// Wi*/Wh*: wih/whh gate-permuted (jp = (c/16)*48 + g*16 + (c%16)).
// =====================================================================
__global__ void prep_k(const float* __restrict__ w1, const float* __restrict__ w2,
                       const float* __restrict__ wih1, const float* __restrict__ whh1,
                       const float* __restrict__ wih2, const float* __restrict__ whh2,
                       const float* __restrict__ xin,
                       u16* __restrict__ B1h, u16* __restrict__ B1l,
                       u16* __restrict__ B2h, u16* __restrict__ B2l,
                       u16* __restrict__ Wi1h, u16* __restrict__ Wi1l,
                       u16* __restrict__ Wh1h, u16* __restrict__ Wh1l,
                       u16* __restrict__ Wi2h, u16* __restrict__ Wi2l,
                       u16* __restrict__ Wh2h, u16* __restrict__ Wh2l,
                       u16* __restrict__ xh, u16* __restrict__ xl) {
    const int n1 = 3 * D1 * D1;  // 49152
    const int n2 = 3 * D2 * D2;  // 196608
    int t = blockIdx.x * blockDim.x + threadIdx.x;
    if (t < n1) {  // w1 transpose -> B1
        int l = t / (D1 * D1), rem = t - l * (D1 * D1);
        int k = rem / D1, n = rem - k * D1;
        float v = w1[t]; u16 h = f2bf(v);
        int o = (l * D1 + n) * D1 + k;
        B1h[o] = h; B1l[o] = f2bf(v - bf2f(h)); return;
    }
    t -= n1;
    if (t < n2) {  // w2 transpose -> B2
        int l = t / (D2 * D2), rem = t - l * (D2 * D2);
        int k = rem / D2, n = rem - k * D2;
        float v = w2[t]; u16 h = f2bf(v);
        int o = (l * D2 + n) * D2 + k;
        B2h[o] = h; B2l[o] = f2bf(v - bf2f(h)); return;
    }
    t -= n2;
    if (t < n1) {  // wih1 gate-permute
        int j = t / D1, k = t - j * D1;
        int g = j >> 7, c = j & 127;
        int jp = (c >> 4) * 48 + g * 16 + (c & 15);
        float v = wih1[t]; u16 h = f2bf(v);
        Wi1h[jp * D1 + k] = h; Wi1l[jp * D1 + k] = f2bf(v - bf2f(h)); return;
    }
    t -= n1;
    if (t < n1) {  // whh1 gate-permute
        int j = t / D1, k = t - j * D1;
        int g = j >> 7, c = j & 127;
        int jp = (c >> 4) * 48 + g * 16 + (c & 15);
        float v = whh1[t]; u16 h = f2bf(v);
        Wh1h[jp * D1 + k] = h; Wh1l[jp * D1 + k] = f2bf(v - bf2f(h)); return;
    }
    t -= n1;
    if (t < n2) {  // wih2 gate-permute
        int j = t / D2, k = t - j * D2;
        int g = j >> 8, c = j & 255;
        int jp = (c >> 4) * 48 + g * 16 + (c & 15);
        float v = wih2[t]; u16 h = f2bf(v);
        Wi2h[jp * D2 + k] = h; Wi2l[jp * D2 + k] = f2bf(v - bf2f(h)); return;
    }
    t -= n2;
    if (t < n2) {  // whh2 gate-permute
        int j = t / D2, k = t - j * D2;
        int g = j >> 8, c = j & 255;
        int jp = (c >> 4) * 48 + g * 16 + (c & 15);
        float v = whh2[t]; u16 h = f2bf(v);
        Wh2h[jp * D2 + k] = h; Wh2l[jp * D2 + k] = f2bf(v - bf2f(h)); return;
    }
    t -= n2;
    if (t < NN * D1) {  // x init (bf16 hi/lo, stride 128)
        float v = xin[t];
        u16 h = f2bf(v);
        xh[t] = h;
        xl[t] = f2bf(v - bf2f(h));
    }
}

// zero cols 128..255 of a layer-2 x buffer (stride 256)
__global__ void pad_k(u16* __restrict__ xh, u16* __restrict__ xl) {
    int t = blockIdx.x * blockDim.x + threadIdx.x;
    if (t >= NN * 128) return;
    int n = t >> 7, c = 128 + (t & 127);
    xh[n * 256 + c] = 0;
    xl[n * 256 + c] = 0;
}

__global__ void pool_init_k(unsigned* __restrict__ pool) {
    int t = blockIdx.x * blockDim.x + threadIdx.x;
    if (t < NG * D2) pool[t] = 0x007FFFFFu;  // mapped(-inf)
}

__global__ void fc_k(const unsigned* __restrict__ pool, const float* __restrict__ w,
                     const float* __restrict__ b, float* __restrict__ out) {
    int t = blockIdx.x * blockDim.x + threadIdx.x;
    if (t >= NG * 6) return;
    int g = t / 6, o = t - g * 6;
    float s = b[o];
    for (int c = 0; c < D2; ++c) {
        unsigned u = pool[g * D2 + c];
        unsigned bits = (u & 0x80000000u) ? (u ^ 0x80000000u) : ~u;
        s += __uint_as_float(bits) * w[o * D2 + c];
    }
    out[t] = s;
}

// =======================================================================
extern "C" void kernel_launch(void* const* d_in, const int* in_sizes, int n_in,
                              void* d_out, int out_size, void* d_ws, size_t ws_size,
                              hipStream_t stream) {
    const float* x_in = (const float*)d_in[0];
    const int* ei = (const int*)d_in[1];
    const int* src = ei;
    const int* dst = ei + NE;
    const int* batch = (const int*)d_in[2];
    const float* w1   = (const float*)d_in[3];
    const float* wih1 = (const float*)d_in[4];
    const float* whh1 = (const float*)d_in[5];
    const float* bih1 = (const float*)d_in[6];
    const float* bhh1 = (const float*)d_in[7];
    const float* w2   = (const float*)d_in[8];
    const float* wih2 = (const float*)d_in[9];
    const float* whh2 = (const float*)d_in[10];
    const float* bih2 = (const float*)d_in[11];
    const float* bhh2 = (const float*)d_in[12];
    const float* fcw  = (const float*)d_in[13];
    const float* fcb  = (const float*)d_in[14];
    float* out = (float*)d_out;

    // ---- workspace (~66 MB) ----
    float* ws = (float*)d_ws;
    float* mbuf = ws;                              // [NNP,256] fp32
    u16* a_h  = (u16*)(mbuf + (size_t)NNP * 256);  // [NNP,256]
    u16* a_l  = a_h + (size_t)NNP * 256;
    u16* xA0h = a_l + (size_t)NNP * 256;           // [NNP,128] ping
    u16* xA0l = xA0h + (size_t)NNP * 128;
    u16* xA1h = xA0l + (size_t)NNP * 128;          // [NNP,128] pong
    u16* xA1l = xA1h + (size_t)NNP * 128;
    u16* xB0h = xA1l + (size_t)NNP * 128;          // [NNP,256] ping
    u16* xB0l = xB0h + (size_t)NNP * 256;
    u16* xB1h = xB0l + (size_t)NNP * 256;          // [NNP,256] pong
    u16* xB1l = xB1h + (size_t)NNP * 256;
    u16* B1h  = xB1l + (size_t)NNP * 256;          // [3][128][128]
    u16* B1l  = B1h + 3 * D1 * D1;
    u16* B2h  = B1l + 3 * D1 * D1;                 // [3][256][256]
    u16* B2l  = B2h + 3 * D2 * D2;
    u16* Wi1h = B2l + 3 * D2 * D2;                 // [384,128] permuted
    u16* Wi1l = Wi1h + 3 * D1 * D1;
    u16* Wh1h = Wi1l + 3 * D1 * D1;
    u16* Wh1l = Wh1h + 3 * D1 * D1;
    u16* Wi2h = Wh1l + 3 * D1 * D1;                // [768,256] permuted
    u16* Wi2l = Wi2h + 3 * D2 * D2;
    u16* Wh2h = Wi2l + 3 * D2 * D2;
    u16* Wh2l = Wh2h + 3 * D2 * D2;
    int* cnt   = (int*)(Wh2l + 3 * D2 * D2);
    int* off   = cnt + NN;
    int* cur   = off + NN + 1;
    int* elist = cur + NN;
    unsigned* pool = (unsigned*)(elist + NE);

    // ---- CSR + prep + pad + pool init ----
    hipMemsetAsync(cnt, 0, NN * sizeof(int), stream);
    count_k<<<(NE + 255) / 256, 256, 0, stream>>>(dst, cnt);
    scan_k<<<1, 1024, 0, stream>>>(cnt, off, cur);
    fill_k<<<(NE + 255) / 256, 256, 0, stream>>>(src, dst, cur, elist);
    {
        int total = 3 * (3 * D1 * D1) + 3 * (3 * D2 * D2) + NN * D1;
        prep_k<<<(total + 255) / 256, 256, 0, stream>>>(
            w1, w2, wih1, whh1, wih2, whh2, x_in,
            B1h, B1l, B2h, B2l, Wi1h, Wi1l, Wh1h, Wh1l,
            Wi2h, Wi2l, Wh2h, Wh2l, xA0h, xA0l);
    }
    pad_k<<<(NN * 128 + 255) / 256, 256, 0, stream>>>(xB0h, xB0l);
    pad_k<<<(NN * 128 + 255) / 256, 256, 0, stream>>>(xB1h, xB1l);
    pool_init_k<<<(NG * D2 + 255) / 256, 256, 0, stream>>>(pool);

    // swizzled 1-D grids for giqru: 80 * (C/32) blocks
    const int G1 = 80 * (D1 / 32);  // 320
    const int G2 = 80 * (D2 / 32);  // 640
    const int GG1 = (NN * (D1 / 4) + 255) / 256;
    const int GG2 = (NN * (D2 / 4) + 255) / 256;

    // ---------------- layer 1 (C = 128) ----------------
    // it 0: xA0 -> xA1 ; it 1: xA1 -> xA0 ; it 2: xA0 -> xB0 (relu, stride 256)
    mm_k<<<dim3(MT, 1), 256, 0, stream>>>(xA0h, xA0l, B1h, B1l, mbuf, D1);
    gather_k<D1><<<GG1, 256, 0, stream>>>(mbuf, off, elist, a_h, a_l);
    giqru_k<0, 128><<<G1, 256, 0, stream>>>(
        a_h, a_l, xA0h, xA0l, Wi1h, Wi1l, Wh1h, Wh1l, bih1, bhh1,
        xA1h, xA1l, nullptr, nullptr, D1);

    mm_k<<<dim3(MT, 1), 256, 0, stream>>>(xA1h, xA1l, B1h + D1 * D1, B1l + D1 * D1, mbuf, D1);
    gather_k<D1><<<GG1, 256, 0, stream>>>(mbuf, off, elist, a_h, a_l);
    giqru_k<0, 128><<<G1, 256, 0, stream>>>(
        a_h, a_l, xA1h, xA1l, Wi1h, Wi1l, Wh1h, Wh1l, bih1, bhh1,
        xA0h, xA0l, nullptr, nullptr, D1);

    mm_k<<<dim3(MT, 1), 256, 0, stream>>>(xA0h, xA0l, B1h + 2 * D1 * D1, B1l + 2 * D1 * D1, mbuf, D1);
    gather_k<D1><<<GG1, 256, 0, stream>>>(mbuf, off, elist, a_h, a_l);
    giqru_k<1, 256><<<G1, 256, 0, stream>>>(
        a_h, a_l, xA0h, xA0l, Wi1h, Wi1l, Wh1h, Wh1l, bih1, bhh1,
        xB0h, xB0l, nullptr, nullptr, D1);

    // ---------------- layer 2 (C = 256) ----------------
    // it 0: xB0 -> xB1 ; it 1: xB1 -> xB0 ; it 2: xB0 -> pool
    mm_k<<<dim3(MT, 2), 256, 0, stream>>>(xB0h, xB0l, B2h, B2l, mbuf, D2);
    gather_k<D2><<<GG2, 256, 0, stream>>>(mbuf, off, elist, a_h, a_l);
    giqru_k<0, 256><<<G2, 256, 0, stream>>>(
        a_h, a_l, xB0h, xB0l, Wi2h, Wi2l, Wh2h, Wh2l, bih2, bhh2,
        xB1h, xB1l, nullptr, nullptr, D2);

    mm_k<<<dim3(MT, 2), 256, 0, stream>>>(xB1h, xB1l, B2h + D2 * D2, B2l + D2 * D2, mbuf, D2);
    gather_k<D2><<<GG2, 256, 0, stream>>>(mbuf, off, elist, a_h, a_l);
    giqru_k<0, 256><<<G2, 256, 0, stream>>>(
        a_h, a_l, xB1h, xB1l, Wi2h, Wi2l, Wh2h, Wh2l, bih2, bhh2,
        xB0h, xB0l, nullptr, nullptr, D2);

    mm_k<<<dim3(MT, 2), 256, 0, stream>>>(xB0h, xB0l, B2h + 2 * D2 * D2, B2l + 2 * D2 * D2, mbuf, D2);
    gather_k<D2><<<GG2, 256, 0, stream>>>(mbuf, off, elist, a_h, a_l);
    giqru_k<2, 256><<<G2, 256, 0, stream>>>(
        a_h, a_l, xB0h, xB0l, Wi2h, Wi2l, Wh2h, Wh2l, bih2, bhh2,
        nullptr, nullptr, batch, pool, D2);

    fc_k<<<1, 512, 0, stream>>>(pool, fcw, fcb, out);
}

// Round 3
// 677.896 us; speedup vs baseline: 1.0506x; 1.0223x over previous
//
#include <hip/hip_runtime.h>

#define NN 10000
#define NNP 10112  // 79*128 padded rows (slack reads harmless, never stored)
#define NE 320000
#define NG 64
#define D1 128
#define D2 256
#define MT 79      // 128-row tiles (giqru)
#define MT64 158   // 64-row tiles (mm)

typedef unsigned short u16;
typedef short v8s __attribute__((ext_vector_type(8)));
typedef float v4f __attribute__((ext_vector_type(4)));

__device__ __forceinline__ u16 f2bf(float x) {
    unsigned u = __float_as_uint(x);
    return (u16)((u + 0x7fffu + ((u >> 16) & 1u)) >> 16);
}
__device__ __forceinline__ float bf2f(u16 b) {
    return __uint_as_float(((unsigned)b) << 16);
}
__device__ __forceinline__ float sigm(float x) { return 1.f / (1.f + __expf(-x)); }
__device__ __forceinline__ float tanh_f(float x) {
    float cx = fminf(fmaxf(x, -15.f), 15.f);
    float e = __expf(2.f * cx);
    return (e - 1.f) / (e + 1.f);
}

#define MF(d, a, b) d = __builtin_amdgcn_mfma_f32_16x16x32_bf16(a, b, d, 0, 0, 0)

// async global->LDS, 16B per lane; LDS dest = wave-uniform base + lane*16
#define GLDS16(gp, lp)                                                         \
    __builtin_amdgcn_global_load_lds(                                          \
        (__attribute__((address_space(1))) unsigned int*)(unsigned long long)(gp), \
        (__attribute__((address_space(3))) unsigned int*)(lp), 16, 0, 0)

// XCD-aware swizzle: 1-D grid of 80*NX blocks. xcd = bid&7; each XCD covers
// row-tile band [xcd*10, xcd*10+10) for ALL col tiles.
#define SWIZZLE(bx, by)                          \
    const int bid_ = blockIdx.x;                 \
    const int l_ = bid_ >> 3;                    \
    const int by = (bid_ & 7) * 10 + l_ % 10;    \
    const int bx = l_ / 10;                      \
    if (by >= MT) return;

// =====================================================================
// mm_k: m = x @ w[it]  (B = w^T, hi/lo split, 3-term). 64x64 tile,
// 4 waves 32x32, BK=32, 2-phase prefetch dbuf (32 KB LDS -> 5 blk/CU).
// Grid (158, K/64).
// =====================================================================
__global__ __launch_bounds__(256)
void mm_k(const u16* __restrict__ Ah, const u16* __restrict__ Al,
          const u16* __restrict__ Bh, const u16* __restrict__ Bl,
          float* __restrict__ Cm, int K) {
    const int by = blockIdx.x, bx = blockIdx.y;
    __shared__ u16 lds[16384];  // 2 bufs x 8192 u16; sub: Ah0 Al2048 Bh4096 Bl6144
    const int tid = threadIdx.x;
    const int wave = tid >> 6, lane = tid & 63;
    const int wm = (wave >> 1) * 32, wn = (wave & 1) * 32;
    const int bm = by * 64, bn = bx * 64;
    const int quad = lane >> 4, r16 = lane & 15;
    const int NK = K >> 5;

    auto STAGE = [&](int b, int k0) {
        size_t ga = (size_t)(bm + lane) * K + k0 + wave * 8;
        size_t gb = (size_t)(bn + lane) * K + k0 + wave * 8;
        int s = b * 8192 + (wave * 64 + lane) * 8;
        GLDS16(Ah + ga, &lds[s]);
        GLDS16(Al + ga, &lds[2048 + s]);
        GLDS16(Bh + gb, &lds[4096 + s]);
        GLDS16(Bl + gb, &lds[6144 + s]);
    };

    v4f acc[2][2] = {};
    STAGE(0, 0);
    __syncthreads();
    int cur = 0;
    for (int ks = 0; ks < NK; ++ks) {
        if (ks + 1 < NK) STAGE(cur ^ 1, (ks + 1) * 32);
        const int bb = cur * 8192;
        v8s af[2], alf[2], bf[2], blf[2];
#pragma unroll
        for (int i = 0; i < 2; ++i) {
            int ra = bb + (quad * 64 + wm + i * 16 + r16) * 8;
            int rb = bb + (quad * 64 + wn + i * 16 + r16) * 8;
            af[i]  = *(const v8s*)&lds[ra];
            alf[i] = *(const v8s*)&lds[2048 + ra];
            bf[i]  = *(const v8s*)&lds[4096 + rb];
            blf[i] = *(const v8s*)&lds[6144 + rb];
        }
#pragma unroll
        for (int i = 0; i < 2; ++i)
#pragma unroll
            for (int j = 0; j < 2; ++j) {
                MF(acc[i][j], af[i], bf[j]);
                MF(acc[i][j], af[i], blf[j]);
                MF(acc[i][j], alf[i], bf[j]);
            }
        __syncthreads();
        cur ^= 1;
    }
#pragma unroll
    for (int i = 0; i < 2; ++i) {
        int gr0 = bm + wm + i * 16 + quad * 4;
#pragma unroll
        for (int j = 0; j < 2; ++j) {
            int gc = bn + wn + j * 16 + r16;
#pragma unroll
            for (int r = 0; r < 4; ++r) {
                int gr = gr0 + r;
                if (gr < NN) Cm[(size_t)gr * K + gc] = acc[i][j][r];
            }
        }
    }
}

// =====================================================================
// giqru_k: unified GEMM  gates = [a | x] @ Wcat^T, K = 2C, plus GRU
// epilogue. Wcat is 4-gate permuted: perm row jp = (c/16)*64 + g*16 +
// (c%16), g in {r=0, z=1, in=2, hn=3}; cols k<C = wih part, k>=C = whh
// part (in's whh half and hn's wih half are zeros -> their MFMAs are
// skipped by phase). acc[i][j]: j IS the gate; all 4 gate values of a
// channel live in the same lane. 128x128 tile, 4 waves 64x64, BK=32,
// 2-phase prefetch dbuf (64 KB LDS). x is a GEMM operand -> ping-pong.
// MODE 0: store stride OS. MODE 1: relu -> stride 256. MODE 2: pool.
// =====================================================================
template<int MODE, int OS>
__global__ __launch_bounds__(256)
void giqru_k(const u16* __restrict__ Ah, const u16* __restrict__ Al,
             const u16* __restrict__ Xh, const u16* __restrict__ Xl,
             const u16* __restrict__ WcH, const u16* __restrict__ WcL,
             const float* __restrict__ bih, const float* __restrict__ bhh,
             u16* __restrict__ xh_out, u16* __restrict__ xl_out,
             const int* __restrict__ batch, unsigned* __restrict__ pool,
             int C) {
    SWIZZLE(bx, by)
    __shared__ u16 lds[32768];  // 2 bufs x 16384 u16; sub: Ah0 Al4096 Bh8192 Bl12288
    const int tid = threadIdx.x;
    const int wave = tid >> 6, lane = tid & 63;
    const int wm = (wave >> 1) * 64, wn = (wave & 1) * 64;
    const int bm = by * 128, bn = bx * 128;
    const int quad = lane >> 4, r16 = lane & 15;
    const int K2 = 2 * C;
    const int NK = K2 >> 5;

    auto STAGE = [&](int b, int k0) {
        const u16* sh = (k0 < C) ? Ah : Xh;
        const u16* sl = (k0 < C) ? Al : Xl;
        const int kk = (k0 < C) ? k0 : k0 - C;
        const int bb = b * 16384;
#pragma unroll
        for (int j = 0; j < 2; ++j) {
            int row = j * 64 + lane;
            size_t ga = (size_t)(bm + row) * C + kk + wave * 8;
            size_t gb = (size_t)(bn + row) * K2 + k0 + wave * 8;
            int s = bb + (wave * 128 + row) * 8;
            GLDS16(sh + ga, &lds[s]);
            GLDS16(sl + ga, &lds[4096 + s]);
            GLDS16(WcH + gb, &lds[8192 + s]);
            GLDS16(WcL + gb, &lds[12288 + s]);
        }
    };

    v4f acc[4][4] = {};
    STAGE(0, 0);
    __syncthreads();
    int cur = 0;
    for (int ks = 0; ks < NK; ++ks) {
        if (ks + 1 < NK) STAGE(cur ^ 1, (ks + 1) * 32);
        const int bb = cur * 16384;
        v8s bhf[4], blf[4];
#pragma unroll
        for (int j = 0; j < 4; ++j) {
            int rb = bb + (quad * 128 + wn + j * 16 + r16) * 8;
            bhf[j] = *(const v8s*)&lds[8192 + rb];
            blf[j] = *(const v8s*)&lds[12288 + rb];
        }
        const bool aphase = (ks * 32) < C;
#pragma unroll
        for (int i = 0; i < 4; ++i) {
            int ra = bb + (quad * 128 + wm + i * 16 + r16) * 8;
            v8s fah = *(const v8s*)&lds[ra];
            v8s fal = *(const v8s*)&lds[4096 + ra];
            MF(acc[i][0], fah, bhf[0]); MF(acc[i][0], fah, blf[0]); MF(acc[i][0], fal, bhf[0]);
            MF(acc[i][1], fah, bhf[1]); MF(acc[i][1], fah, blf[1]); MF(acc[i][1], fal, bhf[1]);
            if (aphase) {
                MF(acc[i][2], fah, bhf[2]); MF(acc[i][2], fah, blf[2]); MF(acc[i][2], fal, bhf[2]);
            } else {
                MF(acc[i][3], fah, bhf[3]); MF(acc[i][3], fah, blf[3]); MF(acc[i][3], fal, bhf[3]);
            }
        }
        __syncthreads();
        cur ^= 1;
    }

    // epilogue: channel c per lane; acc[i][j] j = gate {r,z,in,hn}
    const int c = bx * 32 + (wn ? 16 : 0) + r16;
    const float br = bih[c] + bhh[c];
    const float bz = bih[C + c] + bhh[C + c];
    const float bi_n = bih[2 * C + c];
    const float bh_n = bhh[2 * C + c];
#pragma unroll
    for (int i = 0; i < 4; ++i) {
        int R0 = bm + wm + i * 16 + quad * 4;
#pragma unroll
        for (int r = 0; r < 4; ++r) {
            int R = R0 + r;
            if (R >= NN) continue;
            float rr = sigm(acc[i][0][r] + br);
            float zz = sigm(acc[i][1][r] + bz);
            float nn_ = tanh_f(acc[i][2][r] + bi_n + rr * (acc[i][3][r] + bh_n));
            float h = bf2f(Xh[(size_t)R * C + c]) + bf2f(Xl[(size_t)R * C + c]);
            float o = (1.f - zz) * nn_ + zz * h;
            if (MODE == 2) {
                unsigned b = __float_as_uint(o);
                unsigned u = (b & 0x80000000u) ? ~b : (b | 0x80000000u);
                atomicMax(&pool[batch[R] * 256 + c], u);
            } else {
                if (MODE == 1) o = fmaxf(o, 0.f);
                u16 hh = f2bf(o);
                xh_out[(size_t)R * OS + c] = hh;
                xl_out[(size_t)R * OS + c] = f2bf(o - bf2f(hh));
            }
        }
    }
}

// =====================================================================
// CSR build
// =====================================================================
__global__ void count_k(const int* __restrict__ dst, int* __restrict__ cnt) {
    int e = blockIdx.x * blockDim.x + threadIdx.x;
    if (e < NE) atomicAdd(&cnt[dst[e]], 1);
}

__global__ void scan_k(const int* __restrict__ cnt, int* __restrict__ off,
                       int* __restrict__ cur) {
    __shared__ int ps[1024];
    const int tid = threadIdx.x;
    const int CH = (NN + 1023) / 1024;
    const int base = tid * CH;
    int s = 0;
    for (int i = 0; i < CH; ++i) {
        int idx = base + i;
        if (idx < NN) s += cnt[idx];
    }
    ps[tid] = s;
    __syncthreads();
    for (int d = 1; d < 1024; d <<= 1) {
        int v = (tid >= d) ? ps[tid - d] : 0;
        __syncthreads();
        ps[tid] += v;
        __syncthreads();
    }
    int run = (tid > 0) ? ps[tid - 1] : 0;
    for (int i = 0; i < CH; ++i) {
        int idx = base + i;
        if (idx <= NN) { off[idx] = run; if (idx < NN) cur[idx] = run; }
        if (idx < NN) run += cnt[idx];
    }
}

__global__ void fill_k(const int* __restrict__ src, const int* __restrict__ dst,
                       int* __restrict__ cur, int* __restrict__ elist) {
    int e = blockIdx.x * blockDim.x + threadIdx.x;
    if (e >= NE) return;
    int p = atomicAdd(&cur[dst[e]], 1);
    elist[p] = src[e];
}

// =====================================================================
// CSR gather: a[n,:] = sum m[src,:], bf16 hi/lo out
// =====================================================================
template<int C>
__global__ void gather_k(const float* __restrict__ m, const int* __restrict__ off,
                         const int* __restrict__ elist,
                         u16* __restrict__ ah, u16* __restrict__ al) {
    constexpr int LPN = C / 4;
    int t = blockIdx.x * blockDim.x + threadIdx.x;
    int node = t / LPN;
    if (node >= NN) return;
    int c = (t % LPN) * 4;
    int s0 = off[node], s1 = off[node + 1];
    v4f a0 = 0.f, a1 = 0.f, a2 = 0.f, a3 = 0.f;
    int i = s0;
    for (; i + 4 <= s1; i += 4) {
        int e0 = elist[i], e1 = elist[i + 1], e2 = elist[i + 2], e3 = elist[i + 3];
        v4f v0 = *(const v4f*)(m + (size_t)e0 * C + c);
        v4f v1 = *(const v4f*)(m + (size_t)e1 * C + c);
        v4f v2 = *(const v4f*)(m + (size_t)e2 * C + c);
        v4f v3 = *(const v4f*)(m + (size_t)e3 * C + c);
        a0 += v0; a1 += v1; a2 += v2; a3 += v3;
    }
    for (; i < s1; ++i) {
        int e = elist[i];
        a0 += *(const v4f*)(m + (size_t)e * C + c);
    }
    v4f acc = (a0 + a1) + (a2 + a3);
    ushort4 h, l;
    h.x = f2bf(acc[0]); l.x = f2bf(acc[0] - bf2f(h.x));
    h.y = f2bf(acc[1]); l.y = f2bf(acc[1] - bf2f(h.y));
    h.z = f2bf(acc[2]); l.z = f2bf(acc[2] - bf2f(h.z));
    h.w = f2bf(acc[3]); l.w = f2bf(acc[3] - bf2f(h.w));
    *(ushort4*)(ah + (size_t)node * C + c) = h;
    *(ushort4*)(al + (size_t)node * C + c) = l;
}

// =====================================================================
// prep_k: weight transforms + x init, one launch.
// B1[it] [128,128] = w1[it]^T ; B2[it] [256,256] = w2[it]^T
// Wcat [4C perm rows][2C]: jp = (c/16)*64 + g*16 + (c%16);
//   g=0 (r):  k<C wih[c],       k>=C whh[c]
//   g=1 (z):  k<C wih[C+c],     k>=C whh[C+c]
//   g=2 (in): k<C wih[2C+c],    k>=C 0
//   g=3 (hn): k<C 0,            k>=C whh[2C+c]
// =====================================================================
__global__ void prep_k(const float* __restrict__ w1, const float* __restrict__ w2,
                       const float* __restrict__ wih1, const float* __restrict__ whh1,
                       const float* __restrict__ wih2, const float* __restrict__ whh2,
                       const float* __restrict__ xin,
                       u16* __restrict__ B1h, u16* __restrict__ B1l,
                       u16* __restrict__ B2h, u16* __restrict__ B2l,
                       u16* __restrict__ Wc1h, u16* __restrict__ Wc1l,
                       u16* __restrict__ Wc2h, u16* __restrict__ Wc2l,
                       u16* __restrict__ xh, u16* __restrict__ xl) {
    const int n1 = 3 * D1 * D1;       // 49152
    const int n2 = 3 * D2 * D2;       // 196608
    const int c1 = 4 * D1 * 2 * D1;   // 131072
    const int c2 = 4 * D2 * 2 * D2;   // 524288
    int t = blockIdx.x * blockDim.x + threadIdx.x;
    if (t < n1) {  // w1 transpose -> B1
        int l = t / (D1 * D1), rem = t - l * (D1 * D1);
        int k = rem / D1, n = rem - k * D1;
        float v = w1[t]; u16 h = f2bf(v);
        int o = (l * D1 + n) * D1 + k;
        B1h[o] = h; B1l[o] = f2bf(v - bf2f(h)); return;
    }
    t -= n1;
    if (t < n2) {  // w2 transpose -> B2
        int l = t / (D2 * D2), rem = t - l * (D2 * D2);
        int k = rem / D2, n = rem - k * D2;
        float v = w2[t]; u16 h = f2bf(v);
        int o = (l * D2 + n) * D2 + k;
        B2h[o] = h; B2l[o] = f2bf(v - bf2f(h)); return;
    }
    t -= n2;
    if (t < c1) {  // Wcat1 [512][256]
        int jp = t >> 8, k = t & 255;
        int c = ((jp >> 6) << 4) | (jp & 15);
        int g = (jp >> 4) & 3;
        float v;
        if (g == 0)      v = (k < D1) ? wih1[c * D1 + k]            : whh1[c * D1 + k - D1];
        else if (g == 1) v = (k < D1) ? wih1[(D1 + c) * D1 + k]     : whh1[(D1 + c) * D1 + k - D1];
        else if (g == 2) v = (k < D1) ? wih1[(2 * D1 + c) * D1 + k] : 0.f;
        else             v = (k < D1) ? 0.f : whh1[(2 * D1 + c) * D1 + k - D1];
        u16 h = f2bf(v);
        Wc1h[t] = h; Wc1l[t] = f2bf(v - bf2f(h)); return;
    }
    t -= c1;
    if (t < c2) {  // Wcat2 [1024][512]
        int jp = t >> 9, k = t & 511;
        int c = ((jp >> 6) << 4) | (jp & 15);
        int g = (jp >> 4) & 3;
        float v;
        if (g == 0)      v = (k < D2) ? wih2[c * D2 + k]            : whh2[c * D2 + k - D2];
        else if (g == 1) v = (k < D2) ? wih2[(D2 + c) * D2 + k]     : whh2[(D2 + c) * D2 + k - D2];
        else if (g == 2) v = (k < D2) ? wih2[(2 * D2 + c) * D2 + k] : 0.f;
        else             v = (k < D2) ? 0.f : whh2[(2 * D2 + c) * D2 + k - D2];
        u16 h = f2bf(v);
        Wc2h[t] = h; Wc2l[t] = f2bf(v - bf2f(h)); return;
    }
    t -= c2;
    if (t < NN * D1) {  // x init (bf16 hi/lo, stride 128)
        float v = xin[t];
        u16 h = f2bf(v);
        xh[t] = h;
        xl[t] = f2bf(v - bf2f(h));
    }
}

// zero cols 128..255 of a layer-2 x buffer (stride 256)
__global__ void pad_k(u16* __restrict__ xh, u16* __restrict__ xl) {
    int t = blockIdx.x * blockDim.x + threadIdx.x;
    if (t >= NN * 128) return;
    int n = t >> 7, c = 128 + (t & 127);
    xh[n * 256 + c] = 0;
    xl[n * 256 + c] = 0;
}

__global__ void pool_init_k(unsigned* __restrict__ pool) {
    int t = blockIdx.x * blockDim.x + threadIdx.x;
    if (t < NG * D2) pool[t] = 0x007FFFFFu;  // mapped(-inf)
}

__global__ void fc_k(const unsigned* __restrict__ pool, const float* __restrict__ w,
                     const float* __restrict__ b, float* __restrict__ out) {
    int t = blockIdx.x * blockDim.x + threadIdx.x;
    if (t >= NG * 6) return;
    int g = t / 6, o = t - g * 6;
    float s = b[o];
    for (int c = 0; c < D2; ++c) {
        unsigned u = pool[g * D2 + c];
        unsigned bits = (u & 0x80000000u) ? (u ^ 0x80000000u) : ~u;
        s += __uint_as_float(bits) * w[o * D2 + c];
    }
    out[t] = s;
}

// =======================================================================
extern "C" void kernel_launch(void* const* d_in, const int* in_sizes, int n_in,
                              void* d_out, int out_size, void* d_ws, size_t ws_size,
                              hipStream_t stream) {
    const float* x_in = (const float*)d_in[0];
    const int* ei = (const int*)d_in[1];
    const int* src = ei;
    const int* dst = ei + NE;
    const int* batch = (const int*)d_in[2];
    const float* w1   = (const float*)d_in[3];
    const float* wih1 = (const float*)d_in[4];
    const float* whh1 = (const float*)d_in[5];
    const float* bih1 = (const float*)d_in[6];
    const float* bhh1 = (const float*)d_in[7];
    const float* w2   = (const float*)d_in[8];
    const float* wih2 = (const float*)d_in[9];
    const float* whh2 = (const float*)d_in[10];
    const float* bih2 = (const float*)d_in[11];
    const float* bhh2 = (const float*)d_in[12];
    const float* fcw  = (const float*)d_in[13];
    const float* fcb  = (const float*)d_in[14];
    float* out = (float*)d_out;

    // ---- workspace (~58 MB) ----
    float* ws = (float*)d_ws;
    float* mbuf = ws;                              // [NNP,256] fp32
    u16* a_h  = (u16*)(mbuf + (size_t)NNP * 256);  // [NNP,256]
    u16* a_l  = a_h + (size_t)NNP * 256;
    u16* xA0h = a_l + (size_t)NNP * 256;           // [NNP,128] ping
    u16* xA0l = xA0h + (size_t)NNP * 128;
    u16* xA1h = xA0l + (size_t)NNP * 128;          // [NNP,128] pong
    u16* xA1l = xA1h + (size_t)NNP * 128;
    u16* xB0h = xA1l + (size_t)NNP * 128;          // [NNP,256] ping
    u16* xB0l = xB0h + (size_t)NNP * 256;
    u16* xB1h = xB0l + (size_t)NNP * 256;          // [NNP,256] pong
    u16* xB1l = xB1h + (size_t)NNP * 256;
    u16* B1h  = xB1l + (size_t)NNP * 256;          // [3][128][128]
    u16* B1l  = B1h + 3 * D1 * D1;
    u16* B2h  = B1l + 3 * D1 * D1;                 // [3][256][256]
    u16* B2l  = B2h + 3 * D2 * D2;
    u16* Wc1h = B2l + 3 * D2 * D2;                 // [512][256]
    u16* Wc1l = Wc1h + 4 * D1 * 2 * D1;
    u16* Wc2h = Wc1l + 4 * D1 * 2 * D1;            // [1024][512]
    u16* Wc2l = Wc2h + 4 * D2 * 2 * D2;
    int* cnt   = (int*)(Wc2l + 4 * D2 * 2 * D2);
    int* off   = cnt + NN;
    int* cur   = off + NN + 1;
    int* elist = cur + NN;
    unsigned* pool = (unsigned*)(elist + NE);

    // ---- CSR + prep + pad + pool init ----
    hipMemsetAsync(cnt, 0, NN * sizeof(int), stream);
    count_k<<<(NE + 255) / 256, 256, 0, stream>>>(dst, cnt);
    scan_k<<<1, 1024, 0, stream>>>(cnt, off, cur);
    fill_k<<<(NE + 255) / 256, 256, 0, stream>>>(src, dst, cur, elist);
    {
        int total = 3 * D1 * D1 + 3 * D2 * D2 + 4 * D1 * 2 * D1 + 4 * D2 * 2 * D2 + NN * D1;
        prep_k<<<(total + 255) / 256, 256, 0, stream>>>(
            w1, w2, wih1, whh1, wih2, whh2, x_in,
            B1h, B1l, B2h, B2l, Wc1h, Wc1l, Wc2h, Wc2l, xA0h, xA0l);
    }
    pad_k<<<(NN * 128 + 255) / 256, 256, 0, stream>>>(xB0h, xB0l);
    pool_init_k<<<(NG * D2 + 255) / 256, 256, 0, stream>>>(pool);

    // giqru grids: 80 * (4C/128) swizzled blocks
    const int G1 = 80 * 4;  // 320
    const int G2 = 80 * 8;  // 640
    const int GG1 = (NN * (D1 / 4) + 255) / 256;
    const int GG2 = (NN * (D2 / 4) + 255) / 256;

    // ---------------- layer 1 (C = 128) ----------------
    mm_k<<<dim3(MT64, D1 / 64), 256, 0, stream>>>(xA0h, xA0l, B1h, B1l, mbuf, D1);
    gather_k<D1><<<GG1, 256, 0, stream>>>(mbuf, off, elist, a_h, a_l);
    giqru_k<0, 128><<<G1, 256, 0, stream>>>(
        a_h, a_l, xA0h, xA0l, Wc1h, Wc1l, bih1, bhh1,
        xA1h, xA1l, nullptr, nullptr, D1);

    mm_k<<<dim3(MT64, D1 / 64), 256, 0, stream>>>(xA1h, xA1l, B1h + D1 * D1, B1l + D1 * D1, mbuf, D1);
    gather_k<D1><<<GG1, 256, 0, stream>>>(mbuf, off, elist, a_h, a_l);
    giqru_k<0, 128><<<G1, 256, 0, stream>>>(
        a_h, a_l, xA1h, xA1l, Wc1h, Wc1l, bih1, bhh1,
        xA0h, xA0l, nullptr, nullptr, D1);

    mm_k<<<dim3(MT64, D1 / 64), 256, 0, stream>>>(xA0h, xA0l, B1h + 2 * D1 * D1, B1l + 2 * D1 * D1, mbuf, D1);
    gather_k<D1><<<GG1, 256, 0, stream>>>(mbuf, off, elist, a_h, a_l);
    giqru_k<1, 256><<<G1, 256, 0, stream>>>(
        a_h, a_l, xA0h, xA0l, Wc1h, Wc1l, bih1, bhh1,
        xB0h, xB0l, nullptr, nullptr, D1);

    // ---------------- layer 2 (C = 256) ----------------
    mm_k<<<dim3(MT64, D2 / 64), 256, 0, stream>>>(xB0h, xB0l, B2h, B2l, mbuf, D2);
    gather_k<D2><<<GG2, 256, 0, stream>>>(mbuf, off, elist, a_h, a_l);
    giqru_k<0, 256><<<G2, 256, 0, stream>>>(
        a_h, a_l, xB0h, xB0l, Wc2h, Wc2l, bih2, bhh2,
        xB1h, xB1l, nullptr, nullptr, D2);

    mm_k<<<dim3(MT64, D2 / 64), 256, 0, stream>>>(xB1h, xB1l, B2h + D2 * D2, B2l + D2 * D2, mbuf, D2);
    gather_k<D2><<<GG2, 256, 0, stream>>>(mbuf, off, elist, a_h, a_l);
    giqru_k<0, 256><<<G2, 256, 0, stream>>>(
        a_h, a_l, xB1h, xB1l, Wc2h, Wc2l, bih2, bhh2,
        xB0h, xB0l, nullptr, nullptr, D2);

    mm_k<<<dim3(MT64, D2 / 64), 256, 0, stream>>>(xB0h, xB0l, B2h + 2 * D2 * D2, B2l + 2 * D2 * D2, mbuf, D2);
    gather_k<D2><<<GG2, 256, 0, stream>>>(mbuf, off, elist, a_h, a_l);
    giqru_k<2, 256><<<G2, 256, 0, stream>>>(
        a_h, a_l, xB0h, xB0l, Wc2h, Wc2l, bih2, bhh2,
        nullptr, nullptr, batch, pool, D2);

    fc_k<<<1, 512, 0, stream>>>(pool, fcw, fcb, out);
}

// Round 4
// 584.252 us; speedup vs baseline: 1.2190x; 1.1603x over previous
//
#include <hip/hip_runtime.h>

#define NN 10000
#define NNP 10112  // 158*64 padded rows (slack reads harmless, never stored)
#define NE 320000
#define NG 64
#define D1 128
#define D2 256
#define MT 158     // 64-row tiles

typedef unsigned short u16;
typedef short v8s __attribute__((ext_vector_type(8)));
typedef float v4f __attribute__((ext_vector_type(4)));

__device__ __forceinline__ u16 f2bf(float x) {
    unsigned u = __float_as_uint(x);
    return (u16)((u + 0x7fffu + ((u >> 16) & 1u)) >> 16);
}
__device__ __forceinline__ float bf2f(u16 b) {
    return __uint_as_float(((unsigned)b) << 16);
}
__device__ __forceinline__ float sigm(float x) { return 1.f / (1.f + __expf(-x)); }
__device__ __forceinline__ float tanh_f(float x) {
    float cx = fminf(fmaxf(x, -15.f), 15.f);
    float e = __expf(2.f * cx);
    return (e - 1.f) / (e + 1.f);
}

#define MF(d, a, b) d = __builtin_amdgcn_mfma_f32_16x16x32_bf16(a, b, d, 0, 0, 0)

// async global->LDS, 16B per lane; LDS dest = wave-uniform base + lane*16
#define GLDS16(gp, lp)                                                         \
    __builtin_amdgcn_global_load_lds(                                          \
        (__attribute__((address_space(1))) unsigned int*)(unsigned long long)(gp), \
        (__attribute__((address_space(3))) unsigned int*)(lp), 16, 0, 0)

// XCD-aware swizzle: 1-D grid of 160*NX blocks; xcd = bid&7 owns a 20-row
// band of row-tiles for ALL col tiles (a/x slice stays L2-resident).
#define SWZ(bx, by)                              \
    const int bid_ = blockIdx.x;                 \
    const int l_ = bid_ >> 3;                    \
    const int by = (bid_ & 7) * 20 + l_ % 20;    \
    const int bx = l_ / 20;                      \
    if (by >= MT) return;

// Tiled (k-chunked) global layouts so every GLDS16 is a CONTIGUOUS 1KB DMA:
//   64-row matrices (a, x, mm-B):  idx = ((R/64)*(C/8) + c/8)*512 + (R%64)*8 + c%8
//   128-row Wc blocks:             idx = ((jp/128)*(K2/8) + k/8)*1024 + (jp%128)*8 + k%8
// LDS then holds [kchunk][row][8] = the conflict-free MFMA fragment layout.

// =====================================================================
// mm_k: m = x @ w[it]. 64x64 tile, 4 waves 32x32, BK=32, dbuf 32KB
// (5 blk/CU). All staging contiguous. Grid 160*NX swizzled, NX=K/64.
// =====================================================================
__global__ __launch_bounds__(256)
void mm_k(const u16* __restrict__ Ah, const u16* __restrict__ Al,
          const u16* __restrict__ Bh, const u16* __restrict__ Bl,
          float* __restrict__ Cm, int K) {
    SWZ(bx, by)
    __shared__ u16 lds[16384];  // 2 x 8192: Ahi0 Alo2048 Bhi4096 Blo6144
    const int tid = threadIdx.x;
    const int wave = tid >> 6, lane = tid & 63;
    const int wm = (wave >> 1) * 32, wn = (wave & 1) * 32;
    const int bm = by * 64, bn = bx * 64;
    const int quad = lane >> 4, r16 = lane & 15;
    const int NK = K >> 5;
    const size_t arow = (size_t)(bm >> 6) * (K >> 3);
    const size_t brow = (size_t)(bn >> 6) * (K >> 3);

    auto STAGE = [&](int b, int k0) {
        const u16* pa_h = Ah + (arow + (k0 >> 3)) * 512;
        const u16* pa_l = Al + (arow + (k0 >> 3)) * 512;
        const u16* pb_h = Bh + (brow + (k0 >> 3)) * 512;
        const u16* pb_l = Bl + (brow + (k0 >> 3)) * 512;
        const int B = b * 8192;
#pragma unroll
        for (int t = 0; t < 4; ++t) {
            int u = (t << 2) | wave;
            const u16* gp; int ld;
            if (u < 4)       { gp = pa_h + u * 512;        ld = B + u * 512; }
            else if (u < 8)  { gp = pa_l + (u - 4) * 512;  ld = B + 2048 + (u - 4) * 512; }
            else if (u < 12) { gp = pb_h + (u - 8) * 512;  ld = B + 4096 + (u - 8) * 512; }
            else             { gp = pb_l + (u - 12) * 512; ld = B + 6144 + (u - 12) * 512; }
            GLDS16(gp + lane * 8, &lds[ld]);
        }
    };

    v4f acc[2][2] = {};
    STAGE(0, 0);
    __syncthreads();
    int cur = 0;
    for (int ks = 0; ks < NK; ++ks) {
        if (ks + 1 < NK) STAGE(cur ^ 1, (ks + 1) << 5);
        const int B = cur * 8192;
        v8s af[2], alf[2], bf[2], blf[2];
#pragma unroll
        for (int i = 0; i < 2; ++i) {
            int ra = B + quad * 512 + (wm + i * 16 + r16) * 8;
            int rb = B + quad * 512 + (wn + i * 16 + r16) * 8;
            af[i]  = *(const v8s*)&lds[ra];
            alf[i] = *(const v8s*)&lds[2048 + ra];
            bf[i]  = *(const v8s*)&lds[4096 + rb];
            blf[i] = *(const v8s*)&lds[6144 + rb];
        }
#pragma unroll
        for (int i = 0; i < 2; ++i)
#pragma unroll
            for (int j = 0; j < 2; ++j) {
                MF(acc[i][j], af[i], bf[j]);
                MF(acc[i][j], af[i], blf[j]);
                MF(acc[i][j], alf[i], bf[j]);
            }
        __syncthreads();
        cur ^= 1;
    }
    // m stays NATURAL [row][K] fp32 (gather wants row-contiguous v4f)
#pragma unroll
    for (int i = 0; i < 2; ++i) {
        int gr0 = bm + wm + i * 16 + quad * 4;
#pragma unroll
        for (int j = 0; j < 2; ++j) {
            int gc = bn + wn + j * 16 + r16;
#pragma unroll
            for (int r = 0; r < 4; ++r) {
                int gr = gr0 + r;
                if (gr < NN) Cm[(size_t)gr * K + gc] = acc[i][j][r];
            }
        }
    }
}

// =====================================================================
// giqru_k: gates = [a | x] @ Wcat^T (K2=2C) + GRU epilogue.
// Wcat 4-gate permuted (jp = (c/16)*64 + g*16 + c%16); in/hn zero
// halves skipped by uniform phase. 64 rows x 128 perm cols, 4 waves
// 32x64 (i=2 rows, j=gates). BK=32, dbuf 48KB -> 3 blk/CU.
// acc[i][0]=r, [1]=z, [2]=in, [3]=hn. x ping-pong (GEMM operand).
// MODE 0: store. MODE 1: relu+store (layer1->2). MODE 2: pool atomic.
// =====================================================================
template<int MODE, int OS>
__global__ __launch_bounds__(256)
void giqru_k(const u16* __restrict__ Ah, const u16* __restrict__ Al,
             const u16* __restrict__ Xh, const u16* __restrict__ Xl,
             const u16* __restrict__ WcH, const u16* __restrict__ WcL,
             const float* __restrict__ bih, const float* __restrict__ bhh,
             u16* __restrict__ xh_out, u16* __restrict__ xl_out,
             const int* __restrict__ batch, unsigned* __restrict__ pool,
             int C) {
    SWZ(bx, by)
    __shared__ u16 lds[24576];  // 2 x 12288: Ahi0 Alo2048 Whi4096 Wlo8192
    const int tid = threadIdx.x;
    const int wave = tid >> 6, lane = tid & 63;
    const int wm = (wave >> 1) * 32, wn = (wave & 1) * 64;
    const int bm = by * 64, bn = bx * 128;
    const int quad = lane >> 4, r16 = lane & 15;
    const int K2 = 2 * C;
    const int NK = K2 >> 5;
    const int CCH = C >> 3;
    const size_t arow = (size_t)(bm >> 6) * CCH;
    const size_t wrow = (size_t)(bn >> 7) * (K2 >> 3);

    auto STAGE = [&](int b, int k0) {
        const u16* sh; const u16* sl; int kk;
        if (k0 < C) { sh = Ah; sl = Al; kk = k0; } else { sh = Xh; sl = Xl; kk = k0 - C; }
        const u16* pa_h = sh + (arow + (kk >> 3)) * 512;
        const u16* pa_l = sl + (arow + (kk >> 3)) * 512;
        const u16* pw_h = WcH + (wrow + (k0 >> 3)) * 1024;
        const u16* pw_l = WcL + (wrow + (k0 >> 3)) * 1024;
        const int B = b * 12288;
#pragma unroll
        for (int t = 0; t < 6; ++t) {
            int u = (t << 2) | wave;
            const u16* gp; int ld;
            if (u < 4)       { gp = pa_h + u * 512;        ld = B + u * 512; }
            else if (u < 8)  { gp = pa_l + (u - 4) * 512;  ld = B + 2048 + (u - 4) * 512; }
            else if (u < 16) { gp = pw_h + (u - 8) * 512;  ld = B + 4096 + (u - 8) * 512; }
            else             { gp = pw_l + (u - 16) * 512; ld = B + 8192 + (u - 16) * 512; }
            GLDS16(gp + lane * 8, &lds[ld]);
        }
    };

    v4f acc[2][4] = {};
    STAGE(0, 0);
    __syncthreads();
    int cur = 0;
    for (int ks = 0; ks < NK; ++ks) {
        const int k0 = ks << 5;
        if (ks + 1 < NK) STAGE(cur ^ 1, (ks + 1) << 5);
        const int B = cur * 12288;
        const bool ap = (k0 < C);
        const int g2 = ap ? 2 : 3;
        v8s w0h, w0l, w1h, w1l, w2h, w2l;
        {
            int p0 = B + 4096 + quad * 1024 + (wn + r16) * 8;
            w0h = *(const v8s*)&lds[p0];
            w0l = *(const v8s*)&lds[4096 + p0];
            w1h = *(const v8s*)&lds[p0 + 128];
            w1l = *(const v8s*)&lds[4096 + p0 + 128];
            w2h = *(const v8s*)&lds[p0 + g2 * 128];
            w2l = *(const v8s*)&lds[4096 + p0 + g2 * 128];
        }
#pragma unroll
        for (int i = 0; i < 2; ++i) {
            int ra = B + quad * 512 + (wm + i * 16 + r16) * 8;
            v8s fah = *(const v8s*)&lds[ra];
            v8s fal = *(const v8s*)&lds[2048 + ra];
            MF(acc[i][0], fah, w0h); MF(acc[i][0], fah, w0l); MF(acc[i][0], fal, w0h);
            MF(acc[i][1], fah, w1h); MF(acc[i][1], fah, w1l); MF(acc[i][1], fal, w1h);
            if (ap) {
                MF(acc[i][2], fah, w2h); MF(acc[i][2], fah, w2l); MF(acc[i][2], fal, w2h);
            } else {
                MF(acc[i][3], fah, w2h); MF(acc[i][3], fah, w2l); MF(acc[i][3], fal, w2h);
            }
        }
        __syncthreads();
        cur ^= 1;
    }

    // epilogue: channel c per lane; acc[i][j] j = gate {r,z,in,hn}
    const int c = bx * 32 + (wn ? 16 : 0) + r16;
    const float br = bih[c] + bhh[c];
    const float bz = bih[C + c] + bhh[C + c];
    const float bi_n = bih[2 * C + c];
    const float bh_n = bhh[2 * C + c];
    const int cch = c >> 3, cr = c & 7;
#pragma unroll
    for (int i = 0; i < 2; ++i) {
        int R0 = bm + wm + i * 16 + quad * 4;
#pragma unroll
        for (int r = 0; r < 4; ++r) {
            int R = R0 + r;
            if (R >= NN) continue;
            float rr = sigm(acc[i][0][r] + br);
            float zz = sigm(acc[i][1][r] + bz);
            float nn_ = tanh_f(acc[i][2][r] + bi_n + rr * (acc[i][3][r] + bh_n));
            size_t hx = ((size_t)(R >> 6) * CCH + cch) * 512 + ((R & 63) << 3) + cr;
            float h = bf2f(Xh[hx]) + bf2f(Xl[hx]);
            float o = (1.f - zz) * nn_ + zz * h;
            if (MODE == 2) {
                unsigned b = __float_as_uint(o);
                unsigned u = (b & 0x80000000u) ? ~b : (b | 0x80000000u);
                atomicMax(&pool[batch[R] * 256 + c], u);
            } else {
                if (MODE == 1) o = fmaxf(o, 0.f);
                size_t ox = ((size_t)(R >> 6) * (OS >> 3) + cch) * 512 + ((R & 63) << 3) + cr;
                u16 hh = f2bf(o);
                xh_out[ox] = hh;
                xl_out[ox] = f2bf(o - bf2f(hh));
            }
        }
    }
}

// =====================================================================
// CSR build
// =====================================================================
__global__ void count_k(const int* __restrict__ dst, int* __restrict__ cnt) {
    int e = blockIdx.x * blockDim.x + threadIdx.x;
    if (e < NE) atomicAdd(&cnt[dst[e]], 1);
}

__global__ void scan_k(const int* __restrict__ cnt, int* __restrict__ off,
                       int* __restrict__ cur) {
    __shared__ int ps[1024];
    const int tid = threadIdx.x;
    const int CH = (NN + 1023) / 1024;
    const int base = tid * CH;
    int s = 0;
    for (int i = 0; i < CH; ++i) {
        int idx = base + i;
        if (idx < NN) s += cnt[idx];
    }
    ps[tid] = s;
    __syncthreads();
    for (int d = 1; d < 1024; d <<= 1) {
        int v = (tid >= d) ? ps[tid - d] : 0;
        __syncthreads();
        ps[tid] += v;
        __syncthreads();
    }
    int run = (tid > 0) ? ps[tid - 1] : 0;
    for (int i = 0; i < CH; ++i) {
        int idx = base + i;
        if (idx <= NN) { off[idx] = run; if (idx < NN) cur[idx] = run; }
        if (idx < NN) run += cnt[idx];
    }
}

__global__ void fill_k(const int* __restrict__ src, const int* __restrict__ dst,
                       int* __restrict__ cur, int* __restrict__ elist) {
    int e = blockIdx.x * blockDim.x + threadIdx.x;
    if (e >= NE) return;
    int p = atomicAdd(&cur[dst[e]], 1);
    elist[p] = src[e];
}

// =====================================================================
// CSR gather: a[n,:] = sum m[src,:], bf16 hi/lo out in TILED layout
// =====================================================================
template<int C>
__global__ void gather_k(const float* __restrict__ m, const int* __restrict__ off,
                         const int* __restrict__ elist,
                         u16* __restrict__ ah, u16* __restrict__ al) {
    constexpr int LPN = C / 4;
    int t = blockIdx.x * blockDim.x + threadIdx.x;
    int node = t / LPN;
    if (node >= NN) return;
    int c = (t % LPN) * 4;
    int s0 = off[node], s1 = off[node + 1];
    v4f a0 = 0.f, a1 = 0.f, a2 = 0.f, a3 = 0.f;
    int i = s0;
    for (; i + 4 <= s1; i += 4) {
        int e0 = elist[i], e1 = elist[i + 1], e2 = elist[i + 2], e3 = elist[i + 3];
        v4f v0 = *(const v4f*)(m + (size_t)e0 * C + c);
        v4f v1 = *(const v4f*)(m + (size_t)e1 * C + c);
        v4f v2 = *(const v4f*)(m + (size_t)e2 * C + c);
        v4f v3 = *(const v4f*)(m + (size_t)e3 * C + c);
        a0 += v0; a1 += v1; a2 += v2; a3 += v3;
    }
    for (; i < s1; ++i) {
        int e = elist[i];
        a0 += *(const v4f*)(m + (size_t)e * C + c);
    }
    v4f acc = (a0 + a1) + (a2 + a3);
    ushort4 h, l;
    h.x = f2bf(acc[0]); l.x = f2bf(acc[0] - bf2f(h.x));
    h.y = f2bf(acc[1]); l.y = f2bf(acc[1] - bf2f(h.y));
    h.z = f2bf(acc[2]); l.z = f2bf(acc[2] - bf2f(h.z));
    h.w = f2bf(acc[3]); l.w = f2bf(acc[3] - bf2f(h.w));
    size_t ox = ((size_t)(node >> 6) * (C >> 3) + (c >> 3)) * 512 + ((node & 63) << 3) + (c & 7);
    *(ushort4*)(ah + ox) = h;
    *(ushort4*)(al + ox) = l;
}

// =====================================================================
// prep_k: weight transforms + x init, all into TILED layouts.
// B[it] = w[it]^T as 64-row tiles; Wcat 4-gate permuted 128-row tiles:
//   g=0 (r):  k<C wih[c],       k>=C whh[c]
//   g=1 (z):  k<C wih[C+c],     k>=C whh[C+c]
//   g=2 (in): k<C wih[2C+c],    k>=C 0
//   g=3 (hn): k<C 0,            k>=C whh[2C+c]
// =====================================================================
__global__ void prep_k(const float* __restrict__ w1, const float* __restrict__ w2,
                       const float* __restrict__ wih1, const float* __restrict__ whh1,
                       const float* __restrict__ wih2, const float* __restrict__ whh2,
                       const float* __restrict__ xin,
                       u16* __restrict__ B1h, u16* __restrict__ B1l,
                       u16* __restrict__ B2h, u16* __restrict__ B2l,
                       u16* __restrict__ Wc1h, u16* __restrict__ Wc1l,
                       u16* __restrict__ Wc2h, u16* __restrict__ Wc2l,
                       u16* __restrict__ xh, u16* __restrict__ xl) {
    const int n1 = 3 * D1 * D1;       // 49152
    const int n2 = 3 * D2 * D2;       // 196608
    const int c1 = 4 * D1 * 2 * D1;   // 131072
    const int c2 = 4 * D2 * 2 * D2;   // 524288
    int t = blockIdx.x * blockDim.x + threadIdx.x;
    if (t < n1) {  // w1^T -> B1 tiled (row=n, k)
        int l = t / (D1 * D1), rem = t - l * (D1 * D1);
        int k = rem / D1, n = rem - k * D1;
        float v = w1[t]; u16 h = f2bf(v);
        size_t o = l * D1 * D1 + ((size_t)(n >> 6) * (D1 >> 3) + (k >> 3)) * 512 + ((n & 63) << 3) + (k & 7);
        B1h[o] = h; B1l[o] = f2bf(v - bf2f(h)); return;
    }
    t -= n1;
    if (t < n2) {  // w2^T -> B2 tiled
        int l = t / (D2 * D2), rem = t - l * (D2 * D2);
        int k = rem / D2, n = rem - k * D2;
        float v = w2[t]; u16 h = f2bf(v);
        size_t o = l * D2 * D2 + ((size_t)(n >> 6) * (D2 >> 3) + (k >> 3)) * 512 + ((n & 63) << 3) + (k & 7);
        B2h[o] = h; B2l[o] = f2bf(v - bf2f(h)); return;
    }
    t -= n2;
    if (t < c1) {  // Wcat1 [512 perm][256] tiled
        int jp = t >> 8, k = t & 255;
        int c = ((jp >> 6) << 4) | (jp & 15);
        int g = (jp >> 4) & 3;
        float v;
        if (g == 0)      v = (k < D1) ? wih1[c * D1 + k]            : whh1[c * D1 + k - D1];
        else if (g == 1) v = (k < D1) ? wih1[(D1 + c) * D1 + k]     : whh1[(D1 + c) * D1 + k - D1];
        else if (g == 2) v = (k < D1) ? wih1[(2 * D1 + c) * D1 + k] : 0.f;
        else             v = (k < D1) ? 0.f : whh1[(2 * D1 + c) * D1 + k - D1];
        u16 h = f2bf(v);
        size_t o = ((size_t)(jp >> 7) * 32 + (k >> 3)) * 1024 + ((jp & 127) << 3) + (k & 7);
        Wc1h[o] = h; Wc1l[o] = f2bf(v - bf2f(h)); return;
    }
    t -= c1;
    if (t < c2) {  // Wcat2 [1024 perm][512] tiled
        int jp = t >> 9, k = t & 511;
        int c = ((jp >> 6) << 4) | (jp & 15);
        int g = (jp >> 4) & 3;
        float v;
        if (g == 0)      v = (k < D2) ? wih2[c * D2 + k]            : whh2[c * D2 + k - D2];
        else if (g == 1) v = (k < D2) ? wih2[(D2 + c) * D2 + k]     : whh2[(D2 + c) * D2 + k - D2];
        else if (g == 2) v = (k < D2) ? wih2[(2 * D2 + c) * D2 + k] : 0.f;
        else             v = (k < D2) ? 0.f : whh2[(2 * D2 + c) * D2 + k - D2];
        u16 h = f2bf(v);
        size_t o = ((size_t)(jp >> 7) * 64 + (k >> 3)) * 1024 + ((jp & 127) << 3) + (k & 7);
        Wc2h[o] = h; Wc2l[o] = f2bf(v - bf2f(h)); return;
    }
    t -= c2;
    if (t < NN * D1) {  // x init tiled (C=128)
        int n = t >> 7, cc = t & 127;
        float v = xin[t];
        u16 h = f2bf(v);
        size_t o = ((size_t)(n >> 6) * 16 + (cc >> 3)) * 512 + ((n & 63) << 3) + (cc & 7);
        xh[o] = h;
        xl[o] = f2bf(v - bf2f(h));
    }
}

// zero cols 128..255 of the layer-2 x ping buffer (tiled, C=256)
__global__ void pad_k(u16* __restrict__ xh, u16* __restrict__ xl) {
    int t = blockIdx.x * blockDim.x + threadIdx.x;
    if (t >= NNP * 128) return;
    int n = t >> 7, c = 128 + (t & 127);
    size_t o = ((size_t)(n >> 6) * 32 + (c >> 3)) * 512 + ((n & 63) << 3) + (c & 7);
    xh[o] = 0;
    xl[o] = 0;
}

__global__ void pool_init_k(unsigned* __restrict__ pool) {
    int t = blockIdx.x * blockDim.x + threadIdx.x;
    if (t < NG * D2) pool[t] = 0x007FFFFFu;  // mapped(-inf)
}

__global__ void fc_k(const unsigned* __restrict__ pool, const float* __restrict__ w,
                     const float* __restrict__ b, float* __restrict__ out) {
    int t = blockIdx.x * blockDim.x + threadIdx.x;
    if (t >= NG * 6) return;
    int g = t / 6, o = t - g * 6;
    float s = b[o];
    for (int c = 0; c < D2; ++c) {
        unsigned u = pool[g * D2 + c];
        unsigned bits = (u & 0x80000000u) ? (u ^ 0x80000000u) : ~u;
        s += __uint_as_float(bits) * w[o * D2 + c];
    }
    out[t] = s;
}

// =======================================================================
extern "C" void kernel_launch(void* const* d_in, const int* in_sizes, int n_in,
                              void* d_out, int out_size, void* d_ws, size_t ws_size,
                              hipStream_t stream) {
    const float* x_in = (const float*)d_in[0];
    const int* ei = (const int*)d_in[1];
    const int* src = ei;
    const int* dst = ei + NE;
    const int* batch = (const int*)d_in[2];
    const float* w1   = (const float*)d_in[3];
    const float* wih1 = (const float*)d_in[4];
    const float* whh1 = (const float*)d_in[5];
    const float* bih1 = (const float*)d_in[6];
    const float* bhh1 = (const float*)d_in[7];
    const float* w2   = (const float*)d_in[8];
    const float* wih2 = (const float*)d_in[9];
    const float* whh2 = (const float*)d_in[10];
    const float* bih2 = (const float*)d_in[11];
    const float* bhh2 = (const float*)d_in[12];
    const float* fcw  = (const float*)d_in[13];
    const float* fcb  = (const float*)d_in[14];
    float* out = (float*)d_out;

    // ---- workspace ----
    float* ws = (float*)d_ws;
    float* mbuf = ws;                              // [NNP,256] fp32 (natural)
    u16* a_h  = (u16*)(mbuf + (size_t)NNP * 256);  // tiled [NNP,256]
    u16* a_l  = a_h + (size_t)NNP * 256;
    u16* xA0h = a_l + (size_t)NNP * 256;           // tiled [NNP,128] ping
    u16* xA0l = xA0h + (size_t)NNP * 128;
    u16* xA1h = xA0l + (size_t)NNP * 128;          // pong
    u16* xA1l = xA1h + (size_t)NNP * 128;
    u16* xB0h = xA1l + (size_t)NNP * 128;          // tiled [NNP,256] ping
    u16* xB0l = xB0h + (size_t)NNP * 256;
    u16* xB1h = xB0l + (size_t)NNP * 256;          // pong
    u16* xB1l = xB1h + (size_t)NNP * 256;
    u16* B1h  = xB1l + (size_t)NNP * 256;          // [3] tiled [128,128]
    u16* B1l  = B1h + 3 * D1 * D1;
    u16* B2h  = B1l + 3 * D1 * D1;                 // [3] tiled [256,256]
    u16* B2l  = B2h + 3 * D2 * D2;
    u16* Wc1h = B2l + 3 * D2 * D2;                 // tiled [512,256]
    u16* Wc1l = Wc1h + 4 * D1 * 2 * D1;
    u16* Wc2h = Wc1l + 4 * D1 * 2 * D1;            // tiled [1024,512]
    u16* Wc2l = Wc2h + 4 * D2 * 2 * D2;
    int* cnt   = (int*)(Wc2l + 4 * D2 * 2 * D2);
    int* off   = cnt + NN;
    int* cur   = off + NN + 1;
    int* elist = cur + NN;
    unsigned* pool = (unsigned*)(elist + NE);

    // ---- CSR + prep + pad + pool init ----
    hipMemsetAsync(cnt, 0, NN * sizeof(int), stream);
    count_k<<<(NE + 255) / 256, 256, 0, stream>>>(dst, cnt);
    scan_k<<<1, 1024, 0, stream>>>(cnt, off, cur);
    fill_k<<<(NE + 255) / 256, 256, 0, stream>>>(src, dst, cur, elist);
    {
        int total = 3 * D1 * D1 + 3 * D2 * D2 + 4 * D1 * 2 * D1 + 4 * D2 * 2 * D2 + NN * D1;
        prep_k<<<(total + 255) / 256, 256, 0, stream>>>(
            w1, w2, wih1, whh1, wih2, whh2, x_in,
            B1h, B1l, B2h, B2l, Wc1h, Wc1l, Wc2h, Wc2l, xA0h, xA0l);
    }
    pad_k<<<(NNP * 128 + 255) / 256, 256, 0, stream>>>(xB0h, xB0l);
    pool_init_k<<<(NG * D2 + 255) / 256, 256, 0, stream>>>(pool);

    // swizzled grids: 160 * NX
    const int M1 = 160 * (D1 / 64);   // 320  (mm L1)
    const int M2 = 160 * (D2 / 64);   // 640  (mm L2)
    const int G1 = 160 * (D1 / 32);   // 640  (giqru L1: 512 perm cols / 128)
    const int G2 = 160 * (D2 / 32);   // 1280 (giqru L2: 1024 perm cols / 128)
    const int GG1 = (NN * (D1 / 4) + 255) / 256;
    const int GG2 = (NN * (D2 / 4) + 255) / 256;

    // ---------------- layer 1 (C = 128) ----------------
    mm_k<<<M1, 256, 0, stream>>>(xA0h, xA0l, B1h, B1l, mbuf, D1);
    gather_k<D1><<<GG1, 256, 0, stream>>>(mbuf, off, elist, a_h, a_l);
    giqru_k<0, 128><<<G1, 256, 0, stream>>>(
        a_h, a_l, xA0h, xA0l, Wc1h, Wc1l, bih1, bhh1,
        xA1h, xA1l, nullptr, nullptr, D1);

    mm_k<<<M1, 256, 0, stream>>>(xA1h, xA1l, B1h + D1 * D1, B1l + D1 * D1, mbuf, D1);
    gather_k<D1><<<GG1, 256, 0, stream>>>(mbuf, off, elist, a_h, a_l);
    giqru_k<0, 128><<<G1, 256, 0, stream>>>(
        a_h, a_l, xA1h, xA1l, Wc1h, Wc1l, bih1, bhh1,
        xA0h, xA0l, nullptr, nullptr, D1);

    mm_k<<<M1, 256, 0, stream>>>(xA0h, xA0l, B1h + 2 * D1 * D1, B1l + 2 * D1 * D1, mbuf, D1);
    gather_k<D1><<<GG1, 256, 0, stream>>>(mbuf, off, elist, a_h, a_l);
    giqru_k<1, 256><<<G1, 256, 0, stream>>>(
        a_h, a_l, xA0h, xA0l, Wc1h, Wc1l, bih1, bhh1,
        xB0h, xB0l, nullptr, nullptr, D1);

    // ---------------- layer 2 (C = 256) ----------------
    mm_k<<<M2, 256, 0, stream>>>(xB0h, xB0l, B2h, B2l, mbuf, D2);
    gather_k<D2><<<GG2, 256, 0, stream>>>(mbuf, off, elist, a_h, a_l);
    giqru_k<0, 256><<<G2, 256, 0, stream>>>(
        a_h, a_l, xB0h, xB0l, Wc2h, Wc2l, bih2, bhh2,
        xB1h, xB1l, nullptr, nullptr, D2);

    mm_k<<<M2, 256, 0, stream>>>(xB1h, xB1l, B2h + D2 * D2, B2l + D2 * D2, mbuf, D2);
    gather_k<D2><<<GG2, 256, 0, stream>>>(mbuf, off, elist, a_h, a_l);
    giqru_k<0, 256><<<G2, 256, 0, stream>>>(
        a_h, a_l, xB1h, xB1l, Wc2h, Wc2l, bih2, bhh2,
        xB0h, xB0l, nullptr, nullptr, D2);

    mm_k<<<M2, 256, 0, stream>>>(xB0h, xB0l, B2h + 2 * D2 * D2, B2l + 2 * D2 * D2, mbuf, D2);
    gather_k<D2><<<GG2, 256, 0, stream>>>(mbuf, off, elist, a_h, a_l);
    giqru_k<2, 256><<<G2, 256, 0, stream>>>(
        a_h, a_l, xB0h, xB0l, Wc2h, Wc2l, bih2, bhh2,
        nullptr, nullptr, batch, pool, D2);

    fc_k<<<1, 512, 0, stream>>>(pool, fcw, fcb, out);
}

// Round 7
// 557.599 us; speedup vs baseline: 1.2772x; 1.0478x over previous
//
#include <hip/hip_runtime.h>

#define NN 10000
#define NNP 10112  // 158*64 padded rows (slack reads harmless, never stored)
#define NE 320000
#define NG 64
#define D1 128
#define D2 256
#define MT 158     // 64-row tiles

typedef unsigned short u16;
typedef short v8s __attribute__((ext_vector_type(8)));
typedef float v4f __attribute__((ext_vector_type(4)));

__device__ __forceinline__ u16 f2bf(float x) {
    unsigned u = __float_as_uint(x);
    return (u16)((u + 0x7fffu + ((u >> 16) & 1u)) >> 16);
}
__device__ __forceinline__ float bf2f(u16 b) {
    return __uint_as_float(((unsigned)b) << 16);
}
__device__ __forceinline__ float sigm(float x) { return 1.f / (1.f + __expf(-x)); }
__device__ __forceinline__ float tanh_f(float x) {
    float cx = fminf(fmaxf(x, -15.f), 15.f);
    float e = __expf(2.f * cx);
    return (e - 1.f) / (e + 1.f);
}

#define MF(d, a, b) d = __builtin_amdgcn_mfma_f32_16x16x32_bf16(a, b, d, 0, 0, 0)

// XCD-aware swizzle: 1-D grid of 160*NX blocks; xcd = bid&7 owns a 20-row
// band of row-tiles for ALL col tiles (a/x slice stays L2-resident).
#define SWZ(bx, by)                              \
    const int bid_ = blockIdx.x;                 \
    const int l_ = bid_ >> 3;                    \
    const int by = (bid_ & 7) * 20 + l_ % 20;    \
    const int bx = l_ / 20;                      \
    if (by >= MT) return;

// Tiled (k-chunked) global layouts = the MFMA fragment layout, so GEMM
// kernels read fragments DIRECTLY from global to registers (no LDS, no
// barriers, no waitcnt games — pure register-dataflow pipeline):
//   64-row matrices (a, x, mm-B):  idx = ((R/64)*(C/8) + c/8)*512 + (R%64)*8 + c%8
//   128-row Wc blocks:             idx = ((jp/128)*(K2/8) + k/8)*1024 + (jp%128)*8 + k%8
// A wave's fragment read = 4 x 256B contiguous segments (quad-chunked),
// L2-resident operands; 2x read redundancy (2 waves/fragment) is absorbed
// by L2 (~35 TB/s).

// =====================================================================
// mm_k: m = x @ w[it]. 64x64 tile, 4 waves 32x32, BK=32, no LDS.
// Register ping-pong: load k-step ks+1 while MFMA'ing ks (NK even).
// Grid 160*NX swizzled, NX=K/64.
// =====================================================================
__global__ __launch_bounds__(256)
void mm_k(const u16* __restrict__ Ah, const u16* __restrict__ Al,
          const u16* __restrict__ Bh, const u16* __restrict__ Bl,
          float* __restrict__ Cm, int K) {
    SWZ(bx, by)
    const int tid = threadIdx.x;
    const int wave = tid >> 6, lane = tid & 63;
    const int wm = (wave >> 1) * 32, wn = (wave & 1) * 32;
    const int bm = by * 64, bn = bx * 64;
    const int quad = lane >> 4, r16 = lane & 15;
    const int NK = K >> 5;  // 4 or 8 (even)
    const size_t arow = (size_t)(bm >> 6) * (K >> 3);
    const size_t brow = (size_t)(bn >> 6) * (K >> 3);
    const int aoff0 = (wm + r16) * 8;
    const int boff0 = (wn + r16) * 8;

    auto LOAD = [&](int ks, v8s* af, v8s* alf, v8s* bf, v8s* blf) {
        const size_t ach = (arow + (size_t)(ks << 2) + quad) * 512;
        const size_t bch = (brow + (size_t)(ks << 2) + quad) * 512;
#pragma unroll
        for (int i = 0; i < 2; ++i) {
            af[i]  = *(const v8s*)(Ah + ach + aoff0 + i * 128);
            alf[i] = *(const v8s*)(Al + ach + aoff0 + i * 128);
            bf[i]  = *(const v8s*)(Bh + bch + boff0 + i * 128);
            blf[i] = *(const v8s*)(Bl + bch + boff0 + i * 128);
        }
    };

    v4f acc[2][2] = {};
    auto STEP = [&](v8s* af, v8s* alf, v8s* bf, v8s* blf) {
#pragma unroll
        for (int i = 0; i < 2; ++i)
#pragma unroll
            for (int j = 0; j < 2; ++j) {
                MF(acc[i][j], af[i], bf[j]);
                MF(acc[i][j], af[i], blf[j]);
                MF(acc[i][j], alf[i], bf[j]);
            }
    };

    v8s aA[2], lA[2], bA[2], cA[2];
    v8s aB[2], lB[2], bB[2], cB[2];
    LOAD(0, aA, lA, bA, cA);
    for (int ks = 0; ks < NK; ks += 2) {
        LOAD(ks + 1, aB, lB, bB, cB);
        STEP(aA, lA, bA, cA);
        if (ks + 2 < NK) LOAD(ks + 2, aA, lA, bA, cA);
        STEP(aB, lB, bB, cB);
    }

    // m stays NATURAL [row][K] fp32 (gather wants row-contiguous v4f)
#pragma unroll
    for (int i = 0; i < 2; ++i) {
        int gr0 = bm + wm + i * 16 + quad * 4;
#pragma unroll
        for (int j = 0; j < 2; ++j) {
            int gc = bn + wn + j * 16 + r16;
#pragma unroll
            for (int r = 0; r < 4; ++r) {
                int gr = gr0 + r;
                if (gr < NN) Cm[(size_t)gr * K + gc] = acc[i][j][r];
            }
        }
    }
}

// =====================================================================
// giqru_k: gates = [a | x] @ Wcat^T (K2=2C) + GRU epilogue. No LDS,
// no barriers: fragments straight from tiled global. Wcat 4-gate
// permuted (jp = (c/16)*64 + g*16 + c%16); in/hn zero halves skipped
// by uniform phase. 64 rows x 128 perm cols, 4 waves 32x64.
// acc[i][0]=r, [1]=z, [2]=in, [3]=hn. x ping-pong (GEMM operand).
// MODE 0: store. MODE 1: relu+store (layer1->2). MODE 2: pool atomic.
// =====================================================================
template<int MODE, int OS>
__global__ __launch_bounds__(256)
void giqru_k(const u16* __restrict__ Ah, const u16* __restrict__ Al,
             const u16* __restrict__ Xh, const u16* __restrict__ Xl,
             const u16* __restrict__ WcH, const u16* __restrict__ WcL,
             const float* __restrict__ bih, const float* __restrict__ bhh,
             u16* __restrict__ xh_out, u16* __restrict__ xl_out,
             const int* __restrict__ batch, unsigned* __restrict__ pool,
             int C) {
    SWZ(bx, by)
    const int tid = threadIdx.x;
    const int wave = tid >> 6, lane = tid & 63;
    const int wm = (wave >> 1) * 32, wn = (wave & 1) * 64;
    const int bm = by * 64, bn = bx * 128;
    const int quad = lane >> 4, r16 = lane & 15;
    const int K2 = 2 * C;
    const int NK = K2 >> 5;  // 8 or 16 (even)
    const int CCH = C >> 3;
    const size_t arow = (size_t)(bm >> 6) * CCH;
    const size_t wrow = (size_t)(bn >> 7) * (K2 >> 3);
    const int aoff0 = (wm + r16) * 8;
    const int woff0 = (wn + r16) * 8;

    auto LOAD = [&](int ks, v8s* fah, v8s* fal, v8s* wh, v8s* wl) {
        const int k0 = ks << 5;
        const bool ap = k0 < C;
        const u16* sh = ap ? Ah : Xh;
        const u16* sl = ap ? Al : Xl;
        const int kk = ap ? k0 : k0 - C;
        const size_t ach = (arow + (kk >> 3) + quad) * 512;
        const size_t wch = (wrow + (k0 >> 3) + quad) * 1024;
        const int g2 = ap ? 2 : 3;
#pragma unroll
        for (int i = 0; i < 2; ++i) {
            fah[i] = *(const v8s*)(sh + ach + aoff0 + i * 128);
            fal[i] = *(const v8s*)(sl + ach + aoff0 + i * 128);
        }
        wh[0] = *(const v8s*)(WcH + wch + woff0);
        wl[0] = *(const v8s*)(WcL + wch + woff0);
        wh[1] = *(const v8s*)(WcH + wch + woff0 + 128);
        wl[1] = *(const v8s*)(WcL + wch + woff0 + 128);
        wh[2] = *(const v8s*)(WcH + wch + woff0 + g2 * 128);
        wl[2] = *(const v8s*)(WcL + wch + woff0 + g2 * 128);
    };

    v4f acc[2][4] = {};
    auto STEP = [&](v8s* fah, v8s* fal, v8s* wh, v8s* wl, bool ap) {
#pragma unroll
        for (int i = 0; i < 2; ++i) {
            MF(acc[i][0], fah[i], wh[0]); MF(acc[i][0], fah[i], wl[0]); MF(acc[i][0], fal[i], wh[0]);
            MF(acc[i][1], fah[i], wh[1]); MF(acc[i][1], fah[i], wl[1]); MF(acc[i][1], fal[i], wh[1]);
            if (ap) {
                MF(acc[i][2], fah[i], wh[2]); MF(acc[i][2], fah[i], wl[2]); MF(acc[i][2], fal[i], wh[2]);
            } else {
                MF(acc[i][3], fah[i], wh[2]); MF(acc[i][3], fah[i], wl[2]); MF(acc[i][3], fal[i], wh[2]);
            }
        }
    };

    v8s ahA[2], alA[2], whA[3], wlA[3];
    v8s ahB[2], alB[2], whB[3], wlB[3];
    LOAD(0, ahA, alA, whA, wlA);
    for (int ks = 0; ks < NK; ks += 2) {
        LOAD(ks + 1, ahB, alB, whB, wlB);
        STEP(ahA, alA, whA, wlA, (ks << 5) < C);
        if (ks + 2 < NK) LOAD(ks + 2, ahA, alA, whA, wlA);
        STEP(ahB, alB, whB, wlB, ((ks + 1) << 5) < C);
    }

    // epilogue: channel c per lane; acc[i][j] j = gate {r,z,in,hn}
    const int c = bx * 32 + (wn ? 16 : 0) + r16;
    const float br = bih[c] + bhh[c];
    const float bz = bih[C + c] + bhh[C + c];
    const float bi_n = bih[2 * C + c];
    const float bh_n = bhh[2 * C + c];
    const int cch = c >> 3, cr = c & 7;
#pragma unroll
    for (int i = 0; i < 2; ++i) {
        int R0 = bm + wm + i * 16 + quad * 4;
#pragma unroll
        for (int r = 0; r < 4; ++r) {
            int R = R0 + r;
            if (R >= NN) continue;
            float rr = sigm(acc[i][0][r] + br);
            float zz = sigm(acc[i][1][r] + bz);
            float nn_ = tanh_f(acc[i][2][r] + bi_n + rr * (acc[i][3][r] + bh_n));
            size_t hx = ((size_t)(R >> 6) * CCH + cch) * 512 + ((R & 63) << 3) + cr;
            float h = bf2f(Xh[hx]) + bf2f(Xl[hx]);
            float o = (1.f - zz) * nn_ + zz * h;
            if (MODE == 2) {
                unsigned b = __float_as_uint(o);
                unsigned u = (b & 0x80000000u) ? ~b : (b | 0x80000000u);
                atomicMax(&pool[batch[R] * 256 + c], u);
            } else {
                if (MODE == 1) o = fmaxf(o, 0.f);
                size_t ox = ((size_t)(R >> 6) * (OS >> 3) + cch) * 512 + ((R & 63) << 3) + cr;
                u16 hh = f2bf(o);
                xh_out[ox] = hh;
                xl_out[ox] = f2bf(o - bf2f(hh));
            }
        }
    }
}

// =====================================================================
// CSR build
// =====================================================================
__global__ void count_k(const int* __restrict__ dst, int* __restrict__ cnt) {
    int e = blockIdx.x * blockDim.x + threadIdx.x;
    if (e < NE) atomicAdd(&cnt[dst[e]], 1);
}

__global__ void scan_k(const int* __restrict__ cnt, int* __restrict__ off,
                       int* __restrict__ cur) {
    __shared__ int ps[1024];
    const int tid = threadIdx.x;
    const int CH = (NN + 1023) / 1024;
    const int base = tid * CH;
    int s = 0;
    for (int i = 0; i < CH; ++i) {
        int idx = base + i;
        if (idx < NN) s += cnt[idx];
    }
    ps[tid] = s;
    __syncthreads();
    for (int d = 1; d < 1024; d <<= 1) {
        int v = (tid >= d) ? ps[tid - d] : 0;
        __syncthreads();
        ps[tid] += v;
        __syncthreads();
    }
    int run = (tid > 0) ? ps[tid - 1] : 0;
    for (int i = 0; i < CH; ++i) {
        int idx = base + i;
        if (idx <= NN) { off[idx] = run; if (idx < NN) cur[idx] = run; }
        if (idx < NN) run += cnt[idx];
    }
}

__global__ void fill_k(const int* __restrict__ src, const int* __restrict__ dst,
                       int* __restrict__ cur, int* __restrict__ elist) {
    int e = blockIdx.x * blockDim.x + threadIdx.x;
    if (e >= NE) return;
    int p = atomicAdd(&cur[dst[e]], 1);
    elist[p] = src[e];
}

// =====================================================================
// CSR gather: a[n,:] = sum m[src,:], bf16 hi/lo out in TILED layout.
// Grid bijectively XCD-chunk-swizzled (m204) so a[node] is WRITTEN on
// the same XCD whose giqru band READS it -> giqru a-reads are L2 hits.
// =====================================================================
template<int C>
__global__ void gather_k(const float* __restrict__ m, const int* __restrict__ off,
                         const int* __restrict__ elist,
                         u16* __restrict__ ah, u16* __restrict__ al) {
    constexpr int LPN = C / 4;
    const int GB = gridDim.x;
    const int q = GB >> 3, r = GB & 7;
    const int xx = blockIdx.x & 7, oo = blockIdx.x >> 3;
    const int wg = (xx < r ? xx * (q + 1) : r * (q + 1) + (xx - r) * q) + oo;
    int t = wg * 256 + threadIdx.x;
    int node = t / LPN;
    if (node >= NN) return;
    int c = (t % LPN) * 4;
    int s0 = off[node], s1 = off[node + 1];
    v4f a0 = 0.f, a1 = 0.f, a2 = 0.f, a3 = 0.f;
    int i = s0;
    for (; i + 4 <= s1; i += 4) {
        int e0 = elist[i], e1 = elist[i + 1], e2 = elist[i + 2], e3 = elist[i + 3];
        v4f v0 = *(const v4f*)(m + (size_t)e0 * C + c);
        v4f v1 = *(const v4f*)(m + (size_t)e1 * C + c);
        v4f v2 = *(const v4f*)(m + (size_t)e2 * C + c);
        v4f v3 = *(const v4f*)(m + (size_t)e3 * C + c);
        a0 += v0; a1 += v1; a2 += v2; a3 += v3;
    }
    for (; i < s1; ++i) {
        int e = elist[i];
        a0 += *(const v4f*)(m + (size_t)e * C + c);
    }
    v4f acc = (a0 + a1) + (a2 + a3);
    ushort4 h, l;
    h.x = f2bf(acc[0]); l.x = f2bf(acc[0] - bf2f(h.x));
    h.y = f2bf(acc[1]); l.y = f2bf(acc[1] - bf2f(h.y));
    h.z = f2bf(acc[2]); l.z = f2bf(acc[2] - bf2f(h.z));
    h.w = f2bf(acc[3]); l.w = f2bf(acc[3] - bf2f(h.w));
    size_t ox = ((size_t)(node >> 6) * (C >> 3) + (c >> 3)) * 512 + ((node & 63) << 3) + (c & 7);
    *(ushort4*)(ah + ox) = h;
    *(ushort4*)(al + ox) = l;
}

// =====================================================================
// prep_k: weight transforms + x init, all into TILED layouts.
// B[it] = w[it]^T as 64-row tiles; Wcat 4-gate permuted 128-row tiles:
//   g=0 (r):  k<C wih[c],       k>=C whh[c]
//   g=1 (z):  k<C wih[C+c],     k>=C whh[C+c]
//   g=2 (in): k<C wih[2C+c],    k>=C 0
//   g=3 (hn): k<C 0,            k>=C whh[2C+c]
// =====================================================================
__global__ void prep_k(const float* __restrict__ w1, const float* __restrict__ w2,
                       const float* __restrict__ wih1, const float* __restrict__ whh1,
                       const float* __restrict__ wih2, const float* __restrict__ whh2,
                       const float* __restrict__ xin,
                       u16* __restrict__ B1h, u16* __restrict__ B1l,
                       u16* __restrict__ B2h, u16* __restrict__ B2l,
                       u16* __restrict__ Wc1h, u16* __restrict__ Wc1l,
                       u16* __restrict__ Wc2h, u16* __restrict__ Wc2l,
                       u16* __restrict__ xh, u16* __restrict__ xl) {
    const int n1 = 3 * D1 * D1;       // 49152
    const int n2 = 3 * D2 * D2;       // 196608
    const int c1 = 4 * D1 * 2 * D1;   // 131072
    const int c2 = 4 * D2 * 2 * D2;   // 524288
    int t = blockIdx.x * blockDim.x + threadIdx.x;
    if (t < n1) {  // w1^T -> B1 tiled (row=n, k)
        int l = t / (D1 * D1), rem = t - l * (D1 * D1);
        int k = rem / D1, n = rem - k * D1;
        float v = w1[t]; u16 h = f2bf(v);
        size_t o = l * D1 * D1 + ((size_t)(n >> 6) * (D1 >> 3) + (k >> 3)) * 512 + ((n & 63) << 3) + (k & 7);
        B1h[o] = h; B1l[o] = f2bf(v - bf2f(h)); return;
    }
    t -= n1;
    if (t < n2) {  // w2^T -> B2 tiled
        int l = t / (D2 * D2), rem = t - l * (D2 * D2);
        int k = rem / D2, n = rem - k * D2;
        float v = w2[t]; u16 h = f2bf(v);
        size_t o = l * D2 * D2 + ((size_t)(n >> 6) * (D2 >> 3) + (k >> 3)) * 512 + ((n & 63) << 3) + (k & 7);
        B2h[o] = h; B2l[o] = f2bf(v - bf2f(h)); return;
    }
    t -= n2;
    if (t < c1) {  // Wcat1 [512 perm][256] tiled
        int jp = t >> 8, k = t & 255;
        int c = ((jp >> 6) << 4) | (jp & 15);
        int g = (jp >> 4) & 3;
        float v;
        if (g == 0)      v = (k < D1) ? wih1[c * D1 + k]            : whh1[c * D1 + k - D1];
        else if (g == 1) v = (k < D1) ? wih1[(D1 + c) * D1 + k]     : whh1[(D1 + c) * D1 + k - D1];
        else if (g == 2) v = (k < D1) ? wih1[(2 * D1 + c) * D1 + k] : 0.f;
        else             v = (k < D1) ? 0.f : whh1[(2 * D1 + c) * D1 + k - D1];
        u16 h = f2bf(v);
        size_t o = ((size_t)(jp >> 7) * 32 + (k >> 3)) * 1024 + ((jp & 127) << 3) + (k & 7);
        Wc1h[o] = h; Wc1l[o] = f2bf(v - bf2f(h)); return;
    }
    t -= c1;
    if (t < c2) {  // Wcat2 [1024 perm][512] tiled
        int jp = t >> 9, k = t & 511;
        int c = ((jp >> 6) << 4) | (jp & 15);
        int g = (jp >> 4) & 3;
        float v;
        if (g == 0)      v = (k < D2) ? wih2[c * D2 + k]            : whh2[c * D2 + k - D2];
        else if (g == 1) v = (k < D2) ? wih2[(D2 + c) * D2 + k]     : whh2[(D2 + c) * D2 + k - D2];
        else if (g == 2) v = (k < D2) ? wih2[(2 * D2 + c) * D2 + k] : 0.f;
        else             v = (k < D2) ? 0.f : whh2[(2 * D2 + c) * D2 + k - D2];
        u16 h = f2bf(v);
        size_t o = ((size_t)(jp >> 7) * 64 + (k >> 3)) * 1024 + ((jp & 127) << 3) + (k & 7);
        Wc2h[o] = h; Wc2l[o] = f2bf(v - bf2f(h)); return;
    }
    t -= c2;
    if (t < NN * D1) {  // x init tiled (C=128)
        int n = t >> 7, cc = t & 127;
        float v = xin[t];
        u16 h = f2bf(v);
        size_t o = ((size_t)(n >> 6) * 16 + (cc >> 3)) * 512 + ((n & 63) << 3) + (cc & 7);
        xh[o] = h;
        xl[o] = f2bf(v - bf2f(h));
    }
}

// zero cols 128..255 of the layer-2 x ping buffer (tiled, C=256)
__global__ void pad_k(u16* __restrict__ xh, u16* __restrict__ xl) {
    int t = blockIdx.x * blockDim.x + threadIdx.x;
    if (t >= NNP * 128) return;
    int n = t >> 7, c = 128 + (t & 127);
    size_t o = ((size_t)(n >> 6) * 32 + (c >> 3)) * 512 + ((n & 63) << 3) + (c & 7);
    xh[o] = 0;
    xl[o] = 0;
}

__global__ void pool_init_k(unsigned* __restrict__ pool) {
    int t = blockIdx.x * blockDim.x + threadIdx.x;
    if (t < NG * D2) pool[t] = 0x007FFFFFu;  // mapped(-inf)
}

__global__ void fc_k(const unsigned* __restrict__ pool, const float* __restrict__ w,
                     const float* __restrict__ b, float* __restrict__ out) {
    int t = blockIdx.x * blockDim.x + threadIdx.x;
    if (t >= NG * 6) return;
    int g = t / 6, o = t - g * 6;
    float s = b[o];
    for (int c = 0; c < D2; ++c) {
        unsigned u = pool[g * D2 + c];
        unsigned bits = (u & 0x80000000u) ? (u ^ 0x80000000u) : ~u;
        s += __uint_as_float(bits) * w[o * D2 + c];
    }
    out[t] = s;
}

// =======================================================================
extern "C" void kernel_launch(void* const* d_in, const int* in_sizes, int n_in,
                              void* d_out, int out_size, void* d_ws, size_t ws_size,
                              hipStream_t stream) {
    const float* x_in = (const float*)d_in[0];
    const int* ei = (const int*)d_in[1];
    const int* src = ei;
    const int* dst = ei + NE;
    const int* batch = (const int*)d_in[2];
    const float* w1   = (const float*)d_in[3];
    const float* wih1 = (const float*)d_in[4];
    const float* whh1 = (const float*)d_in[5];
    const float* bih1 = (const float*)d_in[6];
    const float* bhh1 = (const float*)d_in[7];
    const float* w2   = (const float*)d_in[8];
    const float* wih2 = (const float*)d_in[9];
    const float* whh2 = (const float*)d_in[10];
    const float* bih2 = (const float*)d_in[11];
    const float* bhh2 = (const float*)d_in[12];
    const float* fcw  = (const float*)d_in[13];
    const float* fcb  = (const float*)d_in[14];
    float* out = (float*)d_out;

    // ---- workspace ----
    float* ws = (float*)d_ws;
    float* mbuf = ws;                              // [NNP,256] fp32 (natural)
    u16* a_h  = (u16*)(mbuf + (size_t)NNP * 256);  // tiled [NNP,256]
    u16* a_l  = a_h + (size_t)NNP * 256;
    u16* xA0h = a_l + (size_t)NNP * 256;           // tiled [NNP,128] ping
    u16* xA0l = xA0h + (size_t)NNP * 128;
    u16* xA1h = xA0l + (size_t)NNP * 128;          // pong
    u16* xA1l = xA1h + (size_t)NNP * 128;
    u16* xB0h = xA1l + (size_t)NNP * 128;          // tiled [NNP,256] ping
    u16* xB0l = xB0h + (size_t)NNP * 256;
    u16* xB1h = xB0l + (size_t)NNP * 256;          // pong
    u16* xB1l = xB1h + (size_t)NNP * 256;
    u16* B1h  = xB1l + (size_t)NNP * 256;          // [3] tiled [128,128]
    u16* B1l  = B1h + 3 * D1 * D1;
    u16* B2h  = B1l + 3 * D1 * D1;                 // [3] tiled [256,256]
    u16* B2l  = B2h + 3 * D2 * D2;
    u16* Wc1h = B2l + 3 * D2 * D2;                 // tiled [512,256]
    u16* Wc1l = Wc1h + 4 * D1 * 2 * D1;
    u16* Wc2h = Wc1l + 4 * D1 * 2 * D1;            // tiled [1024,512]
    u16* Wc2l = Wc2h + 4 * D2 * 2 * D2;
    int* cnt   = (int*)(Wc2l + 4 * D2 * 2 * D2);
    int* off   = cnt + NN;
    int* cur   = off + NN + 1;
    int* elist = cur + NN;
    unsigned* pool = (unsigned*)(elist + NE);

    // ---- CSR + prep + pad + pool init ----
    hipMemsetAsync(cnt, 0, NN * sizeof(int), stream);
    count_k<<<(NE + 255) / 256, 256, 0, stream>>>(dst, cnt);
    scan_k<<<1, 1024, 0, stream>>>(cnt, off, cur);
    fill_k<<<(NE + 255) / 256, 256, 0, stream>>>(src, dst, cur, elist);
    {
        int total = 3 * D1 * D1 + 3 * D2 * D2 + 4 * D1 * 2 * D1 + 4 * D2 * 2 * D2 + NN * D1;
        prep_k<<<(total + 255) / 256, 256, 0, stream>>>(
            w1, w2, wih1, whh1, wih2, whh2, x_in,
            B1h, B1l, B2h, B2l, Wc1h, Wc1l, Wc2h, Wc2l, xA0h, xA0l);
    }
    pad_k<<<(NNP * 128 + 255) / 256, 256, 0, stream>>>(xB0h, xB0l);
    pool_init_k<<<(NG * D2 + 255) / 256, 256, 0, stream>>>(pool);

    // swizzled grids: 160 * NX
    const int M1 = 160 * (D1 / 64);   // 320  (mm L1)
    const int M2 = 160 * (D2 / 64);   // 640  (mm L2)
    const int G1 = 160 * (D1 / 32);   // 640  (giqru L1: 512 perm cols / 128)
    const int G2 = 160 * (D2 / 32);   // 1280 (giqru L2: 1024 perm cols / 128)
    const int GG1 = (NN * (D1 / 4) + 255) / 256;
    const int GG2 = (NN * (D2 / 4) + 255) / 256;

    // ---------------- layer 1 (C = 128) ----------------
    mm_k<<<M1, 256, 0, stream>>>(xA0h, xA0l, B1h, B1l, mbuf, D1);
    gather_k<D1><<<GG1, 256, 0, stream>>>(mbuf, off, elist, a_h, a_l);
    giqru_k<0, 128><<<G1, 256, 0, stream>>>(
        a_h, a_l, xA0h, xA0l, Wc1h, Wc1l, bih1, bhh1,
        xA1h, xA1l, nullptr, nullptr, D1);

    mm_k<<<M1, 256, 0, stream>>>(xA1h, xA1l, B1h + D1 * D1, B1l + D1 * D1, mbuf, D1);
    gather_k<D1><<<GG1, 256, 0, stream>>>(mbuf, off, elist, a_h, a_l);
    giqru_k<0, 128><<<G1, 256, 0, stream>>>(
        a_h, a_l, xA1h, xA1l, Wc1h, Wc1l, bih1, bhh1,
        xA0h, xA0l, nullptr, nullptr, D1);

    mm_k<<<M1, 256, 0, stream>>>(xA0h, xA0l, B1h + 2 * D1 * D1, B1l + 2 * D1 * D1, mbuf, D1);
    gather_k<D1><<<GG1, 256, 0, stream>>>(mbuf, off, elist, a_h, a_l);
    giqru_k<1, 256><<<G1, 256, 0, stream>>>(
        a_h, a_l, xA0h, xA0l, Wc1h, Wc1l, bih1, bhh1,
        xB0h, xB0l, nullptr, nullptr, D1);

    // ---------------- layer 2 (C = 256) ----------------
    mm_k<<<M2, 256, 0, stream>>>(xB0h, xB0l, B2h, B2l, mbuf, D2);
    gather_k<D2><<<GG2, 256, 0, stream>>>(mbuf, off, elist, a_h, a_l);
    giqru_k<0, 256><<<G2, 256, 0, stream>>>(
        a_h, a_l, xB0h, xB0l, Wc2h, Wc2l, bih2, bhh2,
        xB1h, xB1l, nullptr, nullptr, D2);

    mm_k<<<M2, 256, 0, stream>>>(xB1h, xB1l, B2h + D2 * D2, B2l + D2 * D2, mbuf, D2);
    gather_k<D2><<<GG2, 256, 0, stream>>>(mbuf, off, elist, a_h, a_l);
    giqru_k<0, 256><<<G2, 256, 0, stream>>>(
        a_h, a_l, xB1h, xB1l, Wc2h, Wc2l, bih2, bhh2,
        xB0h, xB0l, nullptr, nullptr, D2);

    mm_k<<<M2, 256, 0, stream>>>(xB0h, xB0l, B2h + 2 * D2 * D2, B2l + 2 * D2 * D2, mbuf, D2);
    gather_k<D2><<<GG2, 256, 0, stream>>>(mbuf, off, elist, a_h, a_l);
    giqru_k<2, 256><<<G2, 256, 0, stream>>>(
        a_h, a_l, xB0h, xB0l, Wc2h, Wc2l, bih2, bhh2,
        nullptr, nullptr, batch, pool, D2);

    fc_k<<<1, 512, 0, stream>>>(pool, fcw, fcb, out);
}